// Round 2
// baseline (2288.197 us; speedup 1.0000x reference)
//
#include <hip/hip_runtime.h>
#include <cstdint>

typedef __bf16 bf16;
typedef __attribute__((ext_vector_type(8))) __bf16 bf16x8;
typedef __attribute__((ext_vector_type(4))) float f32x4;

// async 16B/lane global->LDS (dest = wave-uniform base + lane*16)
#define ASYNC16(gptr, lptr)                                                      \
  __builtin_amdgcn_global_load_lds(                                              \
      (const __attribute__((address_space(1))) unsigned int*)(gptr),             \
      (__attribute__((address_space(3))) unsigned int*)(lptr), 16, 0, 0)

// ---------------------------------------------------------------------------
// C[M,N] = A[M,K] * BT[N,K]^T  (bf16 in, fp32 acc), batched via blockIdx.z:
// batch offset = (z/bdiv)*s?1 + (z%bdiv)*s?2.  Epilogue: v = acc*scale (+bias)
// (relu) (+res) -> bf16 or fp32 store.
// ---------------------------------------------------------------------------
template <int BM, int BN, bool BIAS, bool RELU, bool RES, bool OUTB>
__global__ __launch_bounds__(256) void gemm_bt(
    const bf16* __restrict__ A, const bf16* __restrict__ B, void* __restrict__ C,
    const float* __restrict__ bias, const float* __restrict__ res, int K,
    int lda, int ldb, int ldc, int bdiv, long sA1, long sA2, long sB1, long sB2,
    long sC1, long sC2, float scale)
{
  constexpr int BK = 32;
  constexpr int FM = BM / 32, FN = BN / 32;   // frags per wave (wave tile = BM/2 x BN/2)
  constexpr int CALLS_A = BM / 64, CALLS_B = BN / 64;
  __shared__ __align__(16) bf16 As[BM * BK];
  __shared__ __align__(16) bf16 Bs[BN * BK];
  const int tid = threadIdx.x;
  const int wave = tid >> 6, lane = tid & 63;
  const int zb = blockIdx.z / bdiv, zh = blockIdx.z % bdiv;
  const bf16* Ab = A + zb * sA1 + zh * sA2 + (long)blockIdx.y * BM * lda;
  const bf16* Bb = B + zb * sB1 + zh * sB2 + (long)blockIdx.x * BN * ldb;
  const int rA = lane >> 2, kA = (lane & 3) * 8;  // 4 lanes cover one 32-elem k-row
  const int wm = wave >> 1, wn = wave & 1;
  const int mBase = wm * (BM / 2) + (lane & 15);
  const int nBase = wn * (BN / 2) + (lane & 15);
  const int kOff = (lane >> 4) * 8;

  f32x4 acc[FM][FN] = {};

  for (int k0 = 0; k0 < K; k0 += BK) {
#pragma unroll
    for (int c = 0; c < CALLS_A; ++c) {
      const int cb = (wave * CALLS_A + c) << 10;            // byte offset in tile
      ASYNC16(Ab + (long)((cb >> 6) + rA) * lda + k0 + kA, ((char*)As) + cb);
    }
#pragma unroll
    for (int c = 0; c < CALLS_B; ++c) {
      const int cb = (wave * CALLS_B + c) << 10;
      ASYNC16(Bb + (long)((cb >> 6) + rA) * ldb + k0 + kA, ((char*)Bs) + cb);
    }
    __syncthreads();   // compiler drains vmcnt(0) before s_barrier
    bf16x8 af[FM], bfr[FN];
#pragma unroll
    for (int i = 0; i < FM; ++i)
      af[i] = *(const bf16x8*)&As[(mBase + i * 16) * BK + kOff];
#pragma unroll
    for (int j = 0; j < FN; ++j)
      bfr[j] = *(const bf16x8*)&Bs[(nBase + j * 16) * BK + kOff];
#pragma unroll
    for (int i = 0; i < FM; ++i)
#pragma unroll
      for (int j = 0; j < FN; ++j)
        acc[i][j] = __builtin_amdgcn_mfma_f32_16x16x32_bf16(af[i], bfr[j], acc[i][j], 0, 0, 0);
    __syncthreads();
  }

  // C/D frag: col = lane&15, row = (lane>>4)*4 + r
  const long cBase = zb * sC1 + zh * sC2;
  const int rowB = blockIdx.y * BM + wm * (BM / 2) + ((lane >> 4) << 2);
  const int colB = blockIdx.x * BN + wn * (BN / 2) + (lane & 15);
#pragma unroll
  for (int i = 0; i < FM; ++i) {
#pragma unroll
    for (int j = 0; j < FN; ++j) {
      const int col = colB + j * 16;
      float bv = 0.f;
      if constexpr (BIAS) bv = bias[col];
#pragma unroll
      for (int r = 0; r < 4; ++r) {
        const int row = rowB + i * 16 + r;
        float v = acc[i][j][r] * scale + bv;
        if constexpr (RELU) v = fmaxf(v, 0.f);
        const long idx = cBase + (long)row * ldc + col;
        if constexpr (RES) v += res[idx];
        if constexpr (OUTB) ((bf16*)C)[idx] = (bf16)v;
        else                ((float*)C)[idx] = v;
      }
    }
  }
}

// ---------------------------------------------------------------------------
// Weight prep: W[l][k][n] (fp32) -> WT[l][n][k] (bf16) via LDS-tiled transpose.
// z = l*5 + t, t in {Wq,Wk,Wv,Wo,W2}; Wq/Wk/Wv stack into [2304 x 768] per layer.
// ---------------------------------------------------------------------------
__global__ __launch_bounds__(256) void wprep(
    const float* __restrict__ Wq, const float* __restrict__ Wk,
    const float* __restrict__ Wv, const float* __restrict__ Wo,
    const float* __restrict__ W2, bf16* __restrict__ Tqkv, bf16* __restrict__ To,
    bf16* __restrict__ T2)
{
  const int l = blockIdx.z / 5, t = blockIdx.z % 5;
  const int k0 = blockIdx.x * 64, n0 = blockIdx.y * 64;
  const float* W = (t == 0) ? Wq : (t == 1) ? Wk : (t == 2) ? Wv : (t == 3) ? Wo : W2;
  W += (long)l * 589824;
  __shared__ float tile[64][65];
  const int tid = threadIdx.x;
  const int r = tid >> 2, c = (tid & 3) * 16;
  const float* src = W + (long)(k0 + r) * 768 + n0 + c;
#pragma unroll
  for (int i = 0; i < 4; ++i) {
    f32x4 v = *(const f32x4*)(src + i * 4);
#pragma unroll
    for (int q = 0; q < 4; ++q) tile[r][c + i * 4 + q] = v[q];
  }
  __syncthreads();
  bf16x8 o0, o1;
#pragma unroll
  for (int i = 0; i < 8; ++i) { o0[i] = (bf16)tile[c + i][r]; o1[i] = (bf16)tile[c + 8 + i][r]; }
  bf16* dst;
  if (t < 3)      dst = Tqkv + (long)l * 2304 * 768 + (long)(t * 768 + n0 + r) * 768 + k0 + c;
  else if (t == 3) dst = To + (long)l * 589824 + (long)(n0 + r) * 768 + k0 + c;
  else             dst = T2 + (long)l * 589824 + (long)(n0 + r) * 768 + k0 + c;
  *(bf16x8*)dst = o0;
  *(bf16x8*)(dst + 8) = o1;
}

__global__ void bias_concat(const float* __restrict__ bq, const float* __restrict__ bk,
                            const float* __restrict__ bv, float* __restrict__ o)
{
  const int i = blockIdx.x * 256 + threadIdx.x;
  if (i >= 12 * 2304) return;
  const int l = i / 2304, n = i % 2304;
  o[i] = (n < 768) ? bq[l * 768 + n] : (n < 1536) ? bk[l * 768 + n - 768] : bv[l * 768 + n - 1536];
}

__global__ void xconv(const float* __restrict__ x, float* __restrict__ xf, bf16* __restrict__ xb)
{
  const long i = (long)blockIdx.x * 256 + threadIdx.x;
  const float v = x[i];
  xf[i] = v;
  xb[i] = (bf16)v;
}

// V[b,s,h,d] (inside qkv slab) -> vT[(b*12+h)][d][s]  via 64x64 LDS transpose
__global__ __launch_bounds__(256) void vtrans(const bf16* __restrict__ qkv, bf16* __restrict__ vT)
{
  const int bh = blockIdx.x;
  const int b = bh / 12, h = bh % 12;
  const int s0 = blockIdx.y * 64;
  __shared__ bf16 t[64][72];
  const int tid = threadIdx.x;
  const int r = tid >> 2, c = (tid & 3) * 16;
  const bf16* src = qkv + (long)(b * 512 + s0 + r) * 2304 + 1536 + h * 64 + c;
  const bf16x8 u0 = *(const bf16x8*)src;
  const bf16x8 u1 = *(const bf16x8*)(src + 8);
#pragma unroll
  for (int i = 0; i < 8; ++i) { t[r][c + i] = u0[i]; t[r][c + 8 + i] = u1[i]; }
  __syncthreads();
  bf16x8 w0, w1;
#pragma unroll
  for (int i = 0; i < 8; ++i) { w0[i] = t[c + i][r]; w1[i] = t[c + 8 + i][r]; }
  bf16* dst = vT + ((long)bh * 64 + r) * 512 + s0 + c;
  *(bf16x8*)dst = w0;
  *(bf16x8*)(dst + 8) = w1;
}

// one wave per 512-elem row, in-place softmax (fp32 math)
__global__ __launch_bounds__(256) void softmax_rows(bf16* __restrict__ sc)
{
  const long row = (long)blockIdx.x * 4 + (threadIdx.x >> 6);
  const int lane = threadIdx.x & 63;
  bf16* p = sc + row * 512 + lane * 8;
  bf16x8 v8 = *(bf16x8*)p;
  float v[8];
  float m = -1e30f;
#pragma unroll
  for (int i = 0; i < 8; ++i) { v[i] = (float)v8[i]; m = fmaxf(m, v[i]); }
#pragma unroll
  for (int o = 32; o > 0; o >>= 1) m = fmaxf(m, __shfl_xor(m, o));
  float s = 0.f;
#pragma unroll
  for (int i = 0; i < 8; ++i) { v[i] = __expf(v[i] - m); s += v[i]; }
#pragma unroll
  for (int o = 32; o > 0; o >>= 1) s += __shfl_xor(s, o);
  const float inv = 1.f / s;
  bf16x8 o8;
#pragma unroll
  for (int i = 0; i < 8; ++i) o8[i] = (bf16)(v[i] * inv);
  *(bf16x8*)p = o8;
}

// one 256-thread block per 768-elem row; writes fp32 + bf16 copies
__global__ __launch_bounds__(256) void layernorm_k(
    const float* __restrict__ in, const float* __restrict__ g,
    const float* __restrict__ b, float* __restrict__ outf, bf16* __restrict__ outb)
{
  const long row = blockIdx.x;
  const int tid = threadIdx.x;
  const float* xr = in + row * 768;
  const float v0 = xr[tid], v1 = xr[tid + 256], v2 = xr[tid + 512];
  float s = v0 + v1 + v2;
  float q = v0 * v0 + v1 * v1 + v2 * v2;
#pragma unroll
  for (int o = 32; o > 0; o >>= 1) { s += __shfl_down(s, o); q += __shfl_down(q, o); }
  __shared__ float rs[4], rq[4];
  const int wave = tid >> 6, lane = tid & 63;
  if (lane == 0) { rs[wave] = s; rq[wave] = q; }
  __syncthreads();
  const float st = rs[0] + rs[1] + rs[2] + rs[3];
  const float qt = rq[0] + rq[1] + rq[2] + rq[3];
  const float mean = st * (1.f / 768.f);
  float var = qt * (1.f / 768.f) - mean * mean;
  var = fmaxf(var, 0.f);
  const float rstd = rsqrtf(var + 1e-12f);
  float* of = outf + row * 768;
  bf16* ob = outb + row * 768;
  const float y0 = (v0 - mean) * rstd * g[tid] + b[tid];
  const float y1 = (v1 - mean) * rstd * g[tid + 256] + b[tid + 256];
  const float y2 = (v2 - mean) * rstd * g[tid + 512] + b[tid + 512];
  of[tid] = y0;        of[tid + 256] = y1;        of[tid + 512] = y2;
  ob[tid] = (bf16)y0;  ob[tid + 256] = (bf16)y1;  ob[tid + 512] = (bf16)y2;
}

// ---------------------------------------------------------------------------
extern "C" void kernel_launch(void* const* d_in, const int* in_sizes, int n_in,
                              void* d_out, int out_size, void* d_ws, size_t ws_size,
                              hipStream_t stream)
{
  const float* x   = (const float*)d_in[0];
  const float* Wq  = (const float*)d_in[1];
  const float* bq  = (const float*)d_in[2];
  const float* Wk  = (const float*)d_in[3];
  const float* bk  = (const float*)d_in[4];
  const float* Wv  = (const float*)d_in[5];
  const float* bv  = (const float*)d_in[6];
  const float* Wo  = (const float*)d_in[7];
  const float* bo  = (const float*)d_in[8];
  const float* g1  = (const float*)d_in[9];
  const float* be1 = (const float*)d_in[10];
  const float* W2  = (const float*)d_in[11];
  const float* b2  = (const float*)d_in[12];
  const float* g2  = (const float*)d_in[13];
  const float* be2 = (const float*)d_in[14];
  (void)in_sizes; (void)n_in; (void)out_size; (void)ws_size;

  char* ws = (char*)d_ws;
  size_t off = 0;
  auto alloc = [&](size_t bytes) {
    void* p = ws + off;
    off = (off + bytes + 255) & ~(size_t)255;
    return p;
  };
  bf16*  wTqkv = (bf16*)alloc(12L * 2304 * 768 * 2);
  bf16*  wTo   = (bf16*)alloc(12L * 768 * 768 * 2);
  bf16*  wT2   = (bf16*)alloc(12L * 768 * 768 * 2);
  float* bqkv  = (float*)alloc(12L * 2304 * 4);
  float* xf    = (float*)alloc(4096L * 768 * 4);
  bf16*  xb    = (bf16*)alloc(4096L * 768 * 2);
  bf16*  qkv   = (bf16*)alloc(4096L * 2304 * 2);
  bf16*  sc    = (bf16*)alloc(96L * 512 * 512 * 2);
  bf16*  vT    = (bf16*)alloc(96L * 64 * 512 * 2);
  bf16*  ctx   = (bf16*)alloc(4096L * 768 * 2);
  float* res1  = (float*)alloc(4096L * 768 * 4);
  float* out1f = (float*)alloc(4096L * 768 * 4);
  bf16*  out1b = (bf16*)alloc(4096L * 768 * 2);
  bf16*  h1b   = (bf16*)alloc(4096L * 768 * 2);
  float* res2  = (float*)alloc(4096L * 768 * 4);

  wprep<<<dim3(12, 12, 60), 256, 0, stream>>>(Wq, Wk, Wv, Wo, W2, wTqkv, wTo, wT2);
  bias_concat<<<dim3(108), 256, 0, stream>>>(bq, bk, bv, bqkv);
  xconv<<<dim3(12288), 256, 0, stream>>>(x, xf, xb);

  for (int l = 0; l < 12; ++l) {
    const bf16* wq_l   = wTqkv + (long)l * 2304 * 768;
    const bf16* wo_l   = wTo + (long)l * 589824;
    const bf16* w2_l   = wT2 + (long)l * 589824;
    const float* bqk_l = bqkv + l * 2304;
    float* lnout = (l == 11) ? (float*)d_out : xf;

    // QKV: [4096,768] x [768,2304] -> qkv (bf16, +bias)
    gemm_bt<128, 128, true, false, false, true><<<dim3(18, 32, 1), 256, 0, stream>>>(
        xb, wq_l, qkv, bqk_l, nullptr, 768, 768, 768, 2304,
        1, 0, 0, 0, 0, 0, 0, 1.f);
    // V -> vT[bh][d][s]
    vtrans<<<dim3(96, 8), 256, 0, stream>>>(qkv, vT);
    // scores = Q K^T / 8 per head (bf16 out)
    gemm_bt<128, 128, false, false, false, true><<<dim3(4, 4, 96), 256, 0, stream>>>(
        qkv, qkv + 768, sc, nullptr, nullptr, 64, 2304, 2304, 512,
        12, 512L * 2304, 64, 512L * 2304, 64, 12L * 262144, 262144, 0.125f);
    softmax_rows<<<dim3(12288), 256, 0, stream>>>(sc);
    // ctx = P V per head -> [B,S,H] bf16
    gemm_bt<64, 64, false, false, false, true><<<dim3(1, 8, 96), 256, 0, stream>>>(
        sc, vT, ctx, nullptr, nullptr, 512, 512, 512, 768,
        12, 12L * 262144, 262144, 12L * 32768, 32768, 512L * 768, 64, 1.f);
    // attn out projection + residual(x) -> res1 fp32
    gemm_bt<128, 128, true, false, true, false><<<dim3(6, 32, 1), 256, 0, stream>>>(
        ctx, wo_l, res1, bo + l * 768, xf, 768, 768, 768, 768,
        1, 0, 0, 0, 0, 0, 0, 1.f);
    layernorm_k<<<dim3(4096), 256, 0, stream>>>(res1, g1 + l * 768, be1 + l * 768, out1f, out1b);
    // FF1: relu(out1 @ W2 + b2) -> h1b bf16
    gemm_bt<128, 128, true, true, false, true><<<dim3(6, 32, 1), 256, 0, stream>>>(
        out1b, w2_l, h1b, b2 + l * 768, nullptr, 768, 768, 768, 768,
        1, 0, 0, 0, 0, 0, 0, 1.f);
    // FF2: out1 + relu(h @ W2 + b2) -> res2 fp32
    gemm_bt<128, 128, true, true, true, false><<<dim3(6, 32, 1), 256, 0, stream>>>(
        h1b, w2_l, res2, b2 + l * 768, out1f, 768, 768, 768, 768,
        1, 0, 0, 0, 0, 0, 0, 1.f);
    layernorm_k<<<dim3(4096), 256, 0, stream>>>(res2, g2 + l * 768, be2 + l * 768, lnout, xb);
  }
}

// Round 4
// 2007.292 us; speedup vs baseline: 1.1399x; 1.1399x over previous
//
#include <hip/hip_runtime.h>
#include <cstdint>

typedef __bf16 bf16;
typedef __attribute__((ext_vector_type(8))) __bf16 bf16x8;
typedef __attribute__((ext_vector_type(4))) float f32x4;

// async 16B/lane global->LDS (dest = wave-uniform base + lane*16)
#define ASYNC16(gptr, lptr)                                                      \
  __builtin_amdgcn_global_load_lds(                                              \
      (const __attribute__((address_space(1))) unsigned int*)(gptr),             \
      (__attribute__((address_space(3))) unsigned int*)(lptr), 16, 0, 0)

// ---------------------------------------------------------------------------
// C[M,N] = A[M,K] * BT[N,K]^T  (bf16 in, fp32 acc), batched via blockIdx.z.
// RESMODE: 0 none, 1 fp32 residual. OUTB: bf16 (else fp32) store.
// ---------------------------------------------------------------------------
template <int BM, int BN, bool BIAS, bool RELU, int RESMODE, bool OUTB>
__global__ __launch_bounds__(256) void gemm_bt(
    const bf16* __restrict__ A, const bf16* __restrict__ B, void* __restrict__ C,
    const float* __restrict__ bias, const float* __restrict__ res, int K,
    int lda, int ldb, int ldc, int bdiv, long sA1, long sA2, long sB1, long sB2,
    long sC1, long sC2, float scale)
{
  constexpr int BK = 32;
  constexpr int FM = BM / 32, FN = BN / 32;
  constexpr int CALLS_A = BM / 64, CALLS_B = BN / 64;
  __shared__ __align__(16) bf16 As[BM * BK];
  __shared__ __align__(16) bf16 Bs[BN * BK];
  const int tid = threadIdx.x;
  const int wave = tid >> 6, lane = tid & 63;
  const int zb = blockIdx.z / bdiv, zh = blockIdx.z % bdiv;
  const bf16* Ab = A + zb * sA1 + zh * sA2 + (long)blockIdx.y * BM * lda;
  const bf16* Bb = B + zb * sB1 + zh * sB2 + (long)blockIdx.x * BN * ldb;
  const int rA = lane >> 2, kA = (lane & 3) * 8;
  const int wm = wave >> 1, wn = wave & 1;
  const int mBase = wm * (BM / 2) + (lane & 15);
  const int nBase = wn * (BN / 2) + (lane & 15);
  const int kOff = (lane >> 4) * 8;

  f32x4 acc[FM][FN] = {};

  for (int k0 = 0; k0 < K; k0 += BK) {
#pragma unroll
    for (int c = 0; c < CALLS_A; ++c) {
      const int cb = (wave * CALLS_A + c) << 10;
      ASYNC16(Ab + (long)((cb >> 6) + rA) * lda + k0 + kA, ((char*)As) + cb);
    }
#pragma unroll
    for (int c = 0; c < CALLS_B; ++c) {
      const int cb = (wave * CALLS_B + c) << 10;
      ASYNC16(Bb + (long)((cb >> 6) + rA) * ldb + k0 + kA, ((char*)Bs) + cb);
    }
    __syncthreads();
    bf16x8 af[FM], bfr[FN];
#pragma unroll
    for (int i = 0; i < FM; ++i)
      af[i] = *(const bf16x8*)&As[(mBase + i * 16) * BK + kOff];
#pragma unroll
    for (int j = 0; j < FN; ++j)
      bfr[j] = *(const bf16x8*)&Bs[(nBase + j * 16) * BK + kOff];
#pragma unroll
    for (int i = 0; i < FM; ++i)
#pragma unroll
      for (int j = 0; j < FN; ++j)
        acc[i][j] = __builtin_amdgcn_mfma_f32_16x16x32_bf16(af[i], bfr[j], acc[i][j], 0, 0, 0);
    __syncthreads();
  }

  const long cBase = zb * sC1 + zh * sC2;
  const int rowB = blockIdx.y * BM + wm * (BM / 2) + ((lane >> 4) << 2);
  const int colB = blockIdx.x * BN + wn * (BN / 2) + (lane & 15);
#pragma unroll
  for (int i = 0; i < FM; ++i) {
#pragma unroll
    for (int j = 0; j < FN; ++j) {
      const int col = colB + j * 16;
      float bv = 0.f;
      if constexpr (BIAS) bv = bias[col];
#pragma unroll
      for (int r = 0; r < 4; ++r) {
        const int row = rowB + i * 16 + r;
        float v = acc[i][j][r] * scale + bv;
        if constexpr (RELU) v = fmaxf(v, 0.f);
        const long idx = cBase + (long)row * ldc + col;
        if constexpr (RESMODE == 1) v += res[idx];
        if constexpr (OUTB) ((bf16*)C)[idx] = (bf16)v;
        else                ((float*)C)[idx] = v;
      }
    }
  }
}

// ---------------------------------------------------------------------------
// Fused attention: one block per (q-tile of 64 rows, b*12+h).
// Phase1: S=Q K^T (512 cols in regs, 128/wave). Phase2: softmax (unnorm P ->
// LDS bf16, row sums deferred). Phase3: ctx = P V / rowsum.
// ---------------------------------------------------------------------------
__global__ __launch_bounds__(256, 1) void fattn(
    const bf16* __restrict__ qkv, const bf16* __restrict__ vT,
    bf16* __restrict__ ctx)
{
  __shared__ __align__(16) bf16 Qs[64 * 64];      //  8 KB
  __shared__ __align__(16) bf16 KVs[512 * 64];    // 64 KB (K in ph1, V in ph3)
  __shared__ __align__(16) bf16 Ps[64 * 520];     // 65 KB (pad +8)
  __shared__ float sm[64 * 4];
  __shared__ float ssum[64 * 4];

  const int tid = threadIdx.x, wave = tid >> 6, lane = tid & 63;
  const int bh = blockIdx.y;
  const int b = bh / 12, h = bh % 12;
  const int q0 = blockIdx.x * 64;
  const bf16* Qg = qkv + (long)(b * 512 + q0) * 2304 + h * 64;
  const bf16* Kg = qkv + (long)(b * 512) * 2304 + 768 + h * 64;
  const bf16* Vg = vT + (long)bh * 32768;

  {
    const int r = lane >> 3, cEl = (lane & 7) * 8;
#pragma unroll
    for (int c = 0; c < 2; ++c) {                  // Q: 8 KB
      const int cb = (wave * 2 + c) << 10;
      ASYNC16(Qg + (long)((cb >> 7) + r) * 2304 + cEl, ((char*)Qs) + cb);
    }
#pragma unroll
    for (int c = 0; c < 16; ++c) {                 // K: 64 KB
      const int cb = (wave * 16 + c) << 10;
      ASYNC16(Kg + (long)((cb >> 7) + r) * 2304 + cEl, ((char*)KVs) + cb);
    }
  }
  __syncthreads();

  const int m0 = lane & 15, q = lane >> 4;
  f32x4 acc[4][8] = {};
#pragma unroll
  for (int t = 0; t < 2; ++t) {
    bf16x8 af[4];
#pragma unroll
    for (int i = 0; i < 4; ++i)
      af[i] = *(const bf16x8*)&Qs[(m0 + i * 16) * 64 + t * 32 + q * 8];
#pragma unroll
    for (int j = 0; j < 8; ++j) {
      const int n = wave * 128 + j * 16 + m0;
      bf16x8 bf = *(const bf16x8*)&KVs[n * 64 + t * 32 + q * 8];
#pragma unroll
      for (int i = 0; i < 4; ++i)
        acc[i][j] = __builtin_amdgcn_mfma_f32_16x16x32_bf16(af[i], bf, acc[i][j], 0, 0, 0);
    }
  }

  // wave-local row max over this wave's 128 cols
#pragma unroll
  for (int i = 0; i < 4; ++i)
#pragma unroll
    for (int r = 0; r < 4; ++r) {
      float m = acc[i][0][r];
#pragma unroll
      for (int j = 1; j < 8; ++j) m = fmaxf(m, acc[i][j][r]);
#pragma unroll
      for (int msk = 1; msk < 16; msk <<= 1) m = fmaxf(m, __shfl_xor(m, msk));
      if (m0 == 0) sm[(i * 16 + q * 4 + r) * 4 + wave] = m;
    }
  __syncthreads();   // all waves done with K reads; sm visible

  {  // V loads into KVs (in flight during softmax)
#pragma unroll
    for (int c = 0; c < 16; ++c) {
      const int cb = (wave * 16 + c) << 10;
      ASYNC16(Vg + (long)(cb >> 10) * 512 + lane * 8, ((char*)KVs) + cb);
    }
  }

  const float SCL = 0.125f;
#pragma unroll
  for (int i = 0; i < 4; ++i)
#pragma unroll
    for (int r = 0; r < 4; ++r) {
      const int row = i * 16 + q * 4 + r;
      f32x4 mv = *(const f32x4*)&sm[row * 4];
      const float M = fmaxf(fmaxf(mv[0], mv[1]), fmaxf(mv[2], mv[3])) * SCL;
      float s = 0.f;
#pragma unroll
      for (int j = 0; j < 8; ++j) {
        const float p = __expf(acc[i][j][r] * SCL - M);
        s += p;
        Ps[row * 520 + wave * 128 + j * 16 + m0] = (bf16)p;
      }
#pragma unroll
      for (int msk = 1; msk < 16; msk <<= 1) s += __shfl_xor(s, msk);
      if (m0 == 0) ssum[row * 4 + wave] = s;
    }
  __syncthreads();   // drains V vmcnt + Ps/ssum writes

  // phase 3: wave w owns d-slice [w*16, w*16+16)
  f32x4 cacc[4] = {};
#pragma unroll
  for (int t = 0; t < 16; ++t) {
    bf16x8 bf = *(const bf16x8*)&KVs[(wave * 16 + m0) * 512 + t * 32 + q * 8];
#pragma unroll
    for (int i = 0; i < 4; ++i) {
      bf16x8 af = *(const bf16x8*)&Ps[(i * 16 + m0) * 520 + t * 32 + q * 8];
      cacc[i] = __builtin_amdgcn_mfma_f32_16x16x32_bf16(af, bf, cacc[i], 0, 0, 0);
    }
  }
  const long cbase = (long)(b * 512 + q0) * 768 + h * 64;
  const int col = wave * 16 + m0;
#pragma unroll
  for (int i = 0; i < 4; ++i)
#pragma unroll
    for (int r = 0; r < 4; ++r) {
      const int row = i * 16 + q * 4 + r;
      f32x4 sv = *(const f32x4*)&ssum[row * 4];
      const float inv = 1.f / (sv[0] + sv[1] + sv[2] + sv[3]);
      ctx[cbase + (long)row * 768 + col] = (bf16)(cacc[i][r] * inv);
    }
}

// ---------------------------------------------------------------------------
// Weight prep: W[l][k][n] fp32 -> WT[l][n][k] bf16 (bf16 LDS tile).
// ---------------------------------------------------------------------------
__global__ __launch_bounds__(256) void wprep(
    const float* __restrict__ Wq, const float* __restrict__ Wk,
    const float* __restrict__ Wv, const float* __restrict__ Wo,
    const float* __restrict__ W2, bf16* __restrict__ Tqkv, bf16* __restrict__ To,
    bf16* __restrict__ T2)
{
  const int l = blockIdx.z / 5, t = blockIdx.z % 5;
  const int k0 = blockIdx.x * 64, n0 = blockIdx.y * 64;
  const float* W = (t == 0) ? Wq : (t == 1) ? Wk : (t == 2) ? Wv : (t == 3) ? Wo : W2;
  W += (long)l * 589824;
  __shared__ __align__(16) bf16 tile[64][72];
  const int tid = threadIdx.x;
  const int r = tid >> 2, c = (tid & 3) * 16;
  const float* src = W + (long)(k0 + r) * 768 + n0 + c;
  bf16x8 s0, s1;
#pragma unroll
  for (int i = 0; i < 2; ++i) {
    f32x4 v0 = *(const f32x4*)(src + i * 8);
    f32x4 v1 = *(const f32x4*)(src + i * 8 + 4);
    bf16x8& dstv = i ? s1 : s0;
#pragma unroll
    for (int qq = 0; qq < 4; ++qq) { dstv[qq] = (bf16)v0[qq]; dstv[qq + 4] = (bf16)v1[qq]; }
  }
  *(bf16x8*)&tile[r][c] = s0;
  *(bf16x8*)&tile[r][c + 8] = s1;
  __syncthreads();
  bf16x8 o0, o1;
#pragma unroll
  for (int i = 0; i < 8; ++i) { o0[i] = tile[c + i][r]; o1[i] = tile[c + 8 + i][r]; }
  bf16* dst;
  if (t < 3)       dst = Tqkv + (long)l * 2304 * 768 + (long)(t * 768 + n0 + r) * 768 + k0 + c;
  else if (t == 3) dst = To + (long)l * 589824 + (long)(n0 + r) * 768 + k0 + c;
  else             dst = T2 + (long)l * 589824 + (long)(n0 + r) * 768 + k0 + c;
  *(bf16x8*)dst = o0;
  *(bf16x8*)(dst + 8) = o1;
}

__global__ void bias_concat(const float* __restrict__ bq, const float* __restrict__ bk,
                            const float* __restrict__ bv, float* __restrict__ o)
{
  const int i = blockIdx.x * 256 + threadIdx.x;
  if (i >= 12 * 2304) return;
  const int l = i / 2304, n = i % 2304;
  o[i] = (n < 768) ? bq[l * 768 + n] : (n < 1536) ? bk[l * 768 + n - 768] : bv[l * 768 + n - 1536];
}

__global__ void xconv(const float* __restrict__ x, float* __restrict__ xf, bf16* __restrict__ xb)
{
  const long i = (long)blockIdx.x * 256 + threadIdx.x;
  const float v = x[i];
  xf[i] = v;
  xb[i] = (bf16)v;
}

// V[b,s,h,d] (in qkv slab) -> vT[(b*12+h)][d][s]
__global__ __launch_bounds__(256) void vtrans(const bf16* __restrict__ qkv, bf16* __restrict__ vT)
{
  const int bh = blockIdx.x;
  const int b = bh / 12, h = bh % 12;
  const int s0 = blockIdx.y * 64;
  __shared__ bf16 t[64][72];
  const int tid = threadIdx.x;
  const int r = tid >> 2, c = (tid & 3) * 16;
  const bf16* src = qkv + (long)(b * 512 + s0 + r) * 2304 + 1536 + h * 64 + c;
  const bf16x8 u0 = *(const bf16x8*)src;
  const bf16x8 u1 = *(const bf16x8*)(src + 8);
#pragma unroll
  for (int i = 0; i < 8; ++i) { t[r][c + i] = u0[i]; t[r][c + 8 + i] = u1[i]; }
  __syncthreads();
  bf16x8 w0, w1;
#pragma unroll
  for (int i = 0; i < 8; ++i) { w0[i] = t[c + i][r]; w1[i] = t[c + 8 + i][r]; }
  bf16* dst = vT + ((long)bh * 64 + r) * 512 + s0 + c;
  *(bf16x8*)dst = w0;
  *(bf16x8*)(dst + 8) = w1;
}

// one block per 768-elem row; fp32 in, writes fp32 + bf16 copies
__global__ __launch_bounds__(256) void layernorm_k(
    const float* __restrict__ in, const float* __restrict__ g,
    const float* __restrict__ b, float* __restrict__ outf, bf16* __restrict__ outb)
{
  const long row = blockIdx.x;
  const int tid = threadIdx.x;
  const float* xr = in + row * 768;
  const float v0 = xr[tid], v1 = xr[tid + 256], v2 = xr[tid + 512];
  float s = v0 + v1 + v2;
  float qv = v0 * v0 + v1 * v1 + v2 * v2;
#pragma unroll
  for (int o = 32; o > 0; o >>= 1) { s += __shfl_down(s, o); qv += __shfl_down(qv, o); }
  __shared__ float rs[4], rq[4];
  const int wave = tid >> 6, lane = tid & 63;
  if (lane == 0) { rs[wave] = s; rq[wave] = qv; }
  __syncthreads();
  const float st = rs[0] + rs[1] + rs[2] + rs[3];
  const float qt = rq[0] + rq[1] + rq[2] + rq[3];
  const float mean = st * (1.f / 768.f);
  float var = qt * (1.f / 768.f) - mean * mean;
  var = fmaxf(var, 0.f);
  const float rstd = rsqrtf(var + 1e-12f);
  const float y0 = (v0 - mean) * rstd * g[tid] + b[tid];
  const float y1 = (v1 - mean) * rstd * g[tid + 256] + b[tid + 256];
  const float y2 = (v2 - mean) * rstd * g[tid + 512] + b[tid + 512];
  float* of = outf + row * 768;
  bf16* ob = outb + row * 768;
  of[tid] = y0;        of[tid + 256] = y1;        of[tid + 512] = y2;
  ob[tid] = (bf16)y0;  ob[tid + 256] = (bf16)y1;  ob[tid + 512] = (bf16)y2;
}

// ---------------------------------------------------------------------------
extern "C" void kernel_launch(void* const* d_in, const int* in_sizes, int n_in,
                              void* d_out, int out_size, void* d_ws, size_t ws_size,
                              hipStream_t stream)
{
  const float* x   = (const float*)d_in[0];
  const float* Wq  = (const float*)d_in[1];
  const float* bq  = (const float*)d_in[2];
  const float* Wk  = (const float*)d_in[3];
  const float* bk  = (const float*)d_in[4];
  const float* Wv  = (const float*)d_in[5];
  const float* bv  = (const float*)d_in[6];
  const float* Wo  = (const float*)d_in[7];
  const float* bo  = (const float*)d_in[8];
  const float* g1  = (const float*)d_in[9];
  const float* be1 = (const float*)d_in[10];
  const float* W2  = (const float*)d_in[11];
  const float* b2  = (const float*)d_in[12];
  const float* g2  = (const float*)d_in[13];
  const float* be2 = (const float*)d_in[14];
  (void)in_sizes; (void)n_in; (void)out_size; (void)ws_size;

  char* ws = (char*)d_ws;
  size_t off = 0;
  auto alloc = [&](size_t bytes) {
    void* p = ws + off;
    off = (off + bytes + 255) & ~(size_t)255;
    return p;
  };
  bf16*  wTqkv = (bf16*)alloc(12L * 2304 * 768 * 2);
  bf16*  wTo   = (bf16*)alloc(12L * 768 * 768 * 2);
  bf16*  wT2   = (bf16*)alloc(12L * 768 * 768 * 2);
  float* bqkv  = (float*)alloc(12L * 2304 * 4);
  float* xf    = (float*)alloc(4096L * 768 * 4);
  bf16*  xb    = (bf16*)alloc(4096L * 768 * 2);
  bf16*  qkv   = (bf16*)alloc(4096L * 2304 * 2);
  bf16*  vT    = (bf16*)alloc(96L * 64 * 512 * 2);
  bf16*  ctx   = (bf16*)alloc(4096L * 768 * 2);
  float* res1  = (float*)alloc(4096L * 768 * 4);
  float* out1f = (float*)alloc(4096L * 768 * 4);
  bf16*  out1b = (bf16*)alloc(4096L * 768 * 2);
  bf16*  h1b   = (bf16*)alloc(4096L * 768 * 2);
  float* res2  = (float*)alloc(4096L * 768 * 4);

  wprep<<<dim3(12, 12, 60), 256, 0, stream>>>(Wq, Wk, Wv, Wo, W2, wTqkv, wTo, wT2);
  bias_concat<<<dim3(108), 256, 0, stream>>>(bq, bk, bv, bqkv);
  xconv<<<dim3(12288), 256, 0, stream>>>(x, xf, xb);

  for (int l = 0; l < 12; ++l) {
    const bf16* wq_l   = wTqkv + (long)l * 2304 * 768;
    const bf16* wo_l   = wTo + (long)l * 589824;
    const bf16* w2_l   = wT2 + (long)l * 589824;
    const float* bqk_l = bqkv + l * 2304;
    float* lnout = (l == 11) ? (float*)d_out : xf;

    // QKV: [4096,768] x [768,2304] -> qkv bf16 (+bias)
    gemm_bt<128, 128, true, false, 0, true><<<dim3(18, 32, 1), 256, 0, stream>>>(
        xb, wq_l, qkv, bqk_l, nullptr, 768, 768, 768, 2304,
        1, 0, 0, 0, 0, 0, 0, 1.f);
    vtrans<<<dim3(96, 8), 256, 0, stream>>>(qkv, vT);
    // fused attention -> ctx [B,S,H] bf16
    fattn<<<dim3(8, 96), 256, 0, stream>>>(qkv, vT, ctx);
    // attn out projection + residual(xf fp32) -> res1 fp32
    gemm_bt<128, 64, true, false, 1, false><<<dim3(12, 32, 1), 256, 0, stream>>>(
        ctx, wo_l, res1, bo + l * 768, xf, 768, 768, 768, 768,
        1, 0, 0, 0, 0, 0, 0, 1.f);
    layernorm_k<<<dim3(4096), 256, 0, stream>>>(res1, g1 + l * 768, be1 + l * 768, out1f, out1b);
    // FF1: relu(out1 @ W2 + b2) -> h1b bf16
    gemm_bt<128, 64, true, true, 0, true><<<dim3(12, 32, 1), 256, 0, stream>>>(
        out1b, w2_l, h1b, b2 + l * 768, nullptr, 768, 768, 768, 768,
        1, 0, 0, 0, 0, 0, 0, 1.f);
    // FF2: out1(fp32) + relu(h @ W2 + b2) -> res2 fp32
    gemm_bt<128, 64, true, true, 1, false><<<dim3(12, 32, 1), 256, 0, stream>>>(
        h1b, w2_l, res2, b2 + l * 768, out1f, 768, 768, 768, 768,
        1, 0, 0, 0, 0, 0, 0, 1.f);
    layernorm_k<<<dim3(4096), 256, 0, stream>>>(res2, g2 + l * 768, be2 + l * 768, lnout, xb);
  }
}

// Round 5
// 1727.821 us; speedup vs baseline: 1.3243x; 1.1617x over previous
//
#include <hip/hip_runtime.h>
#include <cstdint>

typedef __bf16 bf16;
typedef __attribute__((ext_vector_type(4))) __bf16 bf16x4;
typedef __attribute__((ext_vector_type(8))) __bf16 bf16x8;
typedef __attribute__((ext_vector_type(4))) float f32x4;

// async 16B/lane global->LDS (dest = wave-uniform base + lane*16)
#define ASYNC16(gptr, lptr)                                                      \
  __builtin_amdgcn_global_load_lds(                                              \
      (const __attribute__((address_space(1))) unsigned int*)(gptr),             \
      (__attribute__((address_space(3))) unsigned int*)(lptr), 16, 0, 0)

// ---------------------------------------------------------------------------
// C[M,N] = A[M,K] * BT[N,K]^T (bf16 in, fp32 acc). BK=64 as 2 BK=32 sub-tiles
// (half the barriers vs BK=32; keeps the proven bank-friendly sub-tile layout
// and ASYNC16 contiguity). RESMODE: 0 none, 1 fp32 residual. OUTB: bf16 store.
// VTOUT: for the QKV GEMM, cols>=1536 (V) are also stored transposed to
// vt[(b*12+h)][d][s] as packed 4-row bf16x4 (replaces the vtrans kernel).
// ---------------------------------------------------------------------------
template <int BM, int BN, bool BIAS, bool RELU, int RESMODE, bool OUTB, bool VTOUT>
__global__ __launch_bounds__(256) void gemm_bt(
    const bf16* __restrict__ A, const bf16* __restrict__ B, void* __restrict__ C,
    const float* __restrict__ bias, const float* __restrict__ res,
    bf16* __restrict__ vt, int K,
    int lda, int ldb, int ldc, int bdiv, long sA1, long sA2, long sB1, long sB2,
    long sC1, long sC2, float scale)
{
  constexpr int FM = BM / 32, FN = BN / 32;
  constexpr int CALLS_A = BM / 64, CALLS_B = BN / 64;   // per 32-k sub-tile
  __shared__ __align__(16) bf16 As[2 * BM * 32];
  __shared__ __align__(16) bf16 Bs[2 * BN * 32];
  const int tid = threadIdx.x;
  const int wave = tid >> 6, lane = tid & 63;
  const int zb = blockIdx.z / bdiv, zh = blockIdx.z % bdiv;
  const bf16* Ab = A + zb * sA1 + zh * sA2 + (long)blockIdx.y * BM * lda;
  const bf16* Bb = B + zb * sB1 + zh * sB2 + (long)blockIdx.x * BN * ldb;
  const int rA = lane >> 2, kA = (lane & 3) * 8;   // 1KB chunk = 16 rows x 64B
  const int wm = wave >> 1, wn = wave & 1;
  const int mBase = wm * (BM / 2) + (lane & 15);
  const int nBase = wn * (BN / 2) + (lane & 15);
  const int kOff = (lane >> 4) * 8;

  f32x4 acc[FM][FN] = {};

  for (int k0 = 0; k0 < K; k0 += 64) {
#pragma unroll
    for (int hh = 0; hh < 2; ++hh) {
      const int kh = k0 + hh * 32;
#pragma unroll
      for (int c = 0; c < CALLS_A; ++c) {
        const int cb = (wave * CALLS_A + c) << 10;
        ASYNC16(Ab + (long)((cb >> 6) + rA) * lda + kh + kA,
                ((char*)As) + hh * (BM * 64) + cb);
      }
#pragma unroll
      for (int c = 0; c < CALLS_B; ++c) {
        const int cb = (wave * CALLS_B + c) << 10;
        ASYNC16(Bb + (long)((cb >> 6) + rA) * ldb + kh + kA,
                ((char*)Bs) + hh * (BN * 64) + cb);
      }
    }
    __syncthreads();
#pragma unroll
    for (int t = 0; t < 2; ++t) {
      const bf16* Asub = As + t * BM * 32;
      const bf16* Bsub = Bs + t * BN * 32;
      bf16x8 af[FM], bfr[FN];
#pragma unroll
      for (int i = 0; i < FM; ++i)
        af[i] = *(const bf16x8*)&Asub[(mBase + i * 16) * 32 + kOff];
#pragma unroll
      for (int j = 0; j < FN; ++j)
        bfr[j] = *(const bf16x8*)&Bsub[(nBase + j * 16) * 32 + kOff];
#pragma unroll
      for (int i = 0; i < FM; ++i)
#pragma unroll
        for (int j = 0; j < FN; ++j)
          acc[i][j] = __builtin_amdgcn_mfma_f32_16x16x32_bf16(af[i], bfr[j], acc[i][j], 0, 0, 0);
    }
    __syncthreads();
  }

  // C/D frag: col = lane&15, row = (lane>>4)*4 + r
  const long cBase = zb * sC1 + zh * sC2;
  const int rowB = blockIdx.y * BM + wm * (BM / 2) + ((lane >> 4) << 2);
  const int colB = blockIdx.x * BN + wn * (BN / 2) + (lane & 15);
#pragma unroll
  for (int i = 0; i < FM; ++i) {
    const int row0 = rowB + i * 16;
#pragma unroll
    for (int j = 0; j < FN; ++j) {
      const int col = colB + j * 16;
      float bv = 0.f;
      if constexpr (BIAS) bv = bias[col];
      bf16x4 pk;
#pragma unroll
      for (int r = 0; r < 4; ++r) {
        const int row = row0 + r;
        float v = acc[i][j][r] * scale + bv;
        if constexpr (RELU) v = fmaxf(v, 0.f);
        const long idx = cBase + (long)row * ldc + col;
        if constexpr (RESMODE == 1) v += res[idx];
        if constexpr (OUTB) ((bf16*)C)[idx] = (bf16)v;
        else                ((float*)C)[idx] = v;
        if constexpr (VTOUT) pk[r] = (bf16)v;
      }
      if constexpr (VTOUT) {
        if (col >= 1536) {   // V columns: also store transposed
          const int cc = col - 1536;
          const int h = cc >> 6, d = cc & 63;
          const int b = row0 >> 9, s = row0 & 511;
          *(bf16x4*)&vt[(((long)(b * 12 + h) * 64 + d) << 9) + s] = pk;
        }
      }
    }
  }
}

// ---------------------------------------------------------------------------
// Fused attention, 512 threads (8 waves = 2 row-groups x 4 col-waves), one
// block per (64-q-row tile, b*12+h). Q/K/V LDS chunks XOR-swizzled to break
// 128B-row bank aliasing on fragment reads.
// ---------------------------------------------------------------------------
__global__ __launch_bounds__(512, 1) void fattn(
    const bf16* __restrict__ qkv, const bf16* __restrict__ vT,
    bf16* __restrict__ ctx)
{
  __shared__ __align__(16) bf16 Qs[64 * 64];      //  8 KB
  __shared__ __align__(16) bf16 KVs[512 * 64];    // 64 KB (K ph1, V ph3)
  __shared__ __align__(16) bf16 Ps[64 * 520];     // 65 KB
  __shared__ float sm[64 * 4];
  __shared__ float ssum[64 * 4];

  const int tid = threadIdx.x, wave = tid >> 6, lane = tid & 63;
  const int wg = wave >> 2, wc = wave & 3;
  const int bh = blockIdx.y;
  const int b = bh / 12, h = bh % 12;
  const int q0 = blockIdx.x * 64;
  const bf16* Qg = qkv + (long)(b * 512 + q0) * 2304 + h * 64;
  const bf16* Kg = qkv + (long)(b * 512) * 2304 + 768 + h * 64;
  const bf16* Vg = vT + (long)bh * 32768;

  const int rq = lane >> 3;                       // row within 1KB chunk (8x128B)
  const int kx = (((lane & 7) ^ rq) << 3);        // XOR-swizzled k-offset
  ASYNC16(Qg + (long)(wave * 8 + rq) * 2304 + kx, ((char*)Qs) + (wave << 10));
#pragma unroll
  for (int c = 0; c < 8; ++c) {                   // K: 64KB, 8 chunks/wave
    const int cb = (wave * 8 + c) << 10;
    ASYNC16(Kg + (long)((cb >> 7) + rq) * 2304 + kx, ((char*)KVs) + cb);
  }
  __syncthreads();

  const int m0 = lane & 15, q = lane >> 4;
  const int sw = (m0 & 7);                        // read-side swizzle key
  f32x4 acc[2][8] = {};
#pragma unroll
  for (int t = 0; t < 2; ++t) {
    const int ch = ((t * 4 + q) ^ sw) << 3;
    bf16x8 af[2];
#pragma unroll
    for (int i = 0; i < 2; ++i)
      af[i] = *(const bf16x8*)&Qs[(wg * 32 + i * 16 + m0) * 64 + ch];
#pragma unroll
    for (int j = 0; j < 8; ++j) {
      bf16x8 bf = *(const bf16x8*)&KVs[(wc * 128 + j * 16 + m0) * 64 + ch];
#pragma unroll
      for (int i = 0; i < 2; ++i)
        acc[i][j] = __builtin_amdgcn_mfma_f32_16x16x32_bf16(af[i], bf, acc[i][j], 0, 0, 0);
    }
  }

  // wave-local row max over this wave's 128 cols
#pragma unroll
  for (int i = 0; i < 2; ++i)
#pragma unroll
    for (int r = 0; r < 4; ++r) {
      float m = acc[i][0][r];
#pragma unroll
      for (int j = 1; j < 8; ++j) m = fmaxf(m, acc[i][j][r]);
#pragma unroll
      for (int msk = 1; msk < 16; msk <<= 1) m = fmaxf(m, __shfl_xor(m, msk));
      if (m0 == 0) sm[(wg * 32 + i * 16 + q * 4 + r) * 4 + wc] = m;
    }
  __syncthreads();   // K reads done; sm visible

  {  // V loads into KVs (in flight during softmax); swizzled per d-row
#pragma unroll
    for (int c = 0; c < 8; ++c) {
      const int d = wave * 8 + c;
      const int cb = (wave * 8 + c) << 10;
      ASYNC16(Vg + (long)d * 512 + ((lane ^ c) << 3), ((char*)KVs) + cb);
    }
  }

  const float SCL = 0.125f;
#pragma unroll
  for (int i = 0; i < 2; ++i)
#pragma unroll
    for (int r = 0; r < 4; ++r) {
      const int row = wg * 32 + i * 16 + q * 4 + r;
      f32x4 mv = *(const f32x4*)&sm[row * 4];
      const float M = fmaxf(fmaxf(mv[0], mv[1]), fmaxf(mv[2], mv[3])) * SCL;
      float s = 0.f;
#pragma unroll
      for (int j = 0; j < 8; ++j) {
        const float p = __expf(acc[i][j][r] * SCL - M);
        s += p;
        Ps[row * 520 + wc * 128 + j * 16 + m0] = (bf16)p;
      }
#pragma unroll
      for (int msk = 1; msk < 16; msk <<= 1) s += __shfl_xor(s, msk);
      if (m0 == 0) ssum[row * 4 + wc] = s;
    }
  __syncthreads();   // drains V vmcnt + Ps/ssum writes

  // phase 3: wave (wg,wc) -> rows wg*32..+32, d-cols wc*16..+16
  f32x4 cacc[2] = {};
#pragma unroll
  for (int t = 0; t < 16; ++t) {
    const int ch = ((t * 4 + q) ^ sw) << 3;
    bf16x8 bf = *(const bf16x8*)&KVs[(wc * 16 + m0) * 512 + ch];
#pragma unroll
    for (int i = 0; i < 2; ++i) {
      bf16x8 af = *(const bf16x8*)&Ps[(wg * 32 + i * 16 + m0) * 520 + t * 32 + q * 8];
      cacc[i] = __builtin_amdgcn_mfma_f32_16x16x32_bf16(af, bf, cacc[i], 0, 0, 0);
    }
  }
  const long cbase = (long)(b * 512 + q0) * 768 + h * 64;
  const int col = wc * 16 + m0;
#pragma unroll
  for (int i = 0; i < 2; ++i)
#pragma unroll
    for (int r = 0; r < 4; ++r) {
      const int row = wg * 32 + i * 16 + q * 4 + r;
      f32x4 sv = *(const f32x4*)&ssum[row * 4];
      const float inv = 1.f / (sv[0] + sv[1] + sv[2] + sv[3]);
      ctx[cbase + (long)row * 768 + col] = (bf16)(cacc[i][r] * inv);
    }
}

// ---------------------------------------------------------------------------
// Weight prep: W[l][k][n] fp32 -> WT[l][n][k] bf16 (bf16 LDS tile).
// ---------------------------------------------------------------------------
__global__ __launch_bounds__(256) void wprep(
    const float* __restrict__ Wq, const float* __restrict__ Wk,
    const float* __restrict__ Wv, const float* __restrict__ Wo,
    const float* __restrict__ W2, bf16* __restrict__ Tqkv, bf16* __restrict__ To,
    bf16* __restrict__ T2)
{
  const int l = blockIdx.z / 5, t = blockIdx.z % 5;
  const int k0 = blockIdx.x * 64, n0 = blockIdx.y * 64;
  const float* W = (t == 0) ? Wq : (t == 1) ? Wk : (t == 2) ? Wv : (t == 3) ? Wo : W2;
  W += (long)l * 589824;
  __shared__ __align__(16) bf16 tile[64][72];
  const int tid = threadIdx.x;
  const int r = tid >> 2, c = (tid & 3) * 16;
  const float* src = W + (long)(k0 + r) * 768 + n0 + c;
  bf16x8 s0, s1;
#pragma unroll
  for (int i = 0; i < 2; ++i) {
    f32x4 v0 = *(const f32x4*)(src + i * 8);
    f32x4 v1 = *(const f32x4*)(src + i * 8 + 4);
    bf16x8& dstv = i ? s1 : s0;
#pragma unroll
    for (int qq = 0; qq < 4; ++qq) { dstv[qq] = (bf16)v0[qq]; dstv[qq + 4] = (bf16)v1[qq]; }
  }
  *(bf16x8*)&tile[r][c] = s0;
  *(bf16x8*)&tile[r][c + 8] = s1;
  __syncthreads();
  bf16x8 o0, o1;
#pragma unroll
  for (int i = 0; i < 8; ++i) { o0[i] = tile[c + i][r]; o1[i] = tile[c + 8 + i][r]; }
  bf16* dst;
  if (t < 3)       dst = Tqkv + (long)l * 2304 * 768 + (long)(t * 768 + n0 + r) * 768 + k0 + c;
  else if (t == 3) dst = To + (long)l * 589824 + (long)(n0 + r) * 768 + k0 + c;
  else             dst = T2 + (long)l * 589824 + (long)(n0 + r) * 768 + k0 + c;
  *(bf16x8*)dst = o0;
  *(bf16x8*)(dst + 8) = o1;
}

__global__ void bias_concat(const float* __restrict__ bq, const float* __restrict__ bk,
                            const float* __restrict__ bv, float* __restrict__ o)
{
  const int i = blockIdx.x * 256 + threadIdx.x;
  if (i >= 12 * 2304) return;
  const int l = i / 2304, n = i % 2304;
  o[i] = (n < 768) ? bq[l * 768 + n] : (n < 1536) ? bk[l * 768 + n - 768] : bv[l * 768 + n - 1536];
}

__global__ void xconv(const float* __restrict__ x, float* __restrict__ xf, bf16* __restrict__ xb)
{
  const long i = (long)blockIdx.x * 256 + threadIdx.x;
  const float v = x[i];
  xf[i] = v;
  xb[i] = (bf16)v;
}

// one block per 768-elem row; fp32 in, writes fp32 + bf16 copies
__global__ __launch_bounds__(256) void layernorm_k(
    const float* __restrict__ in, const float* __restrict__ g,
    const float* __restrict__ b, float* __restrict__ outf, bf16* __restrict__ outb)
{
  const long row = blockIdx.x;
  const int tid = threadIdx.x;
  const float* xr = in + row * 768;
  const float v0 = xr[tid], v1 = xr[tid + 256], v2 = xr[tid + 512];
  float s = v0 + v1 + v2;
  float qv = v0 * v0 + v1 * v1 + v2 * v2;
#pragma unroll
  for (int o = 32; o > 0; o >>= 1) { s += __shfl_down(s, o); qv += __shfl_down(qv, o); }
  __shared__ float rs[4], rq[4];
  const int wave = tid >> 6, lane = tid & 63;
  if (lane == 0) { rs[wave] = s; rq[wave] = qv; }
  __syncthreads();
  const float st = rs[0] + rs[1] + rs[2] + rs[3];
  const float qt = rq[0] + rq[1] + rq[2] + rq[3];
  const float mean = st * (1.f / 768.f);
  float var = qt * (1.f / 768.f) - mean * mean;
  var = fmaxf(var, 0.f);
  const float rstd = rsqrtf(var + 1e-12f);
  const float y0 = (v0 - mean) * rstd * g[tid] + b[tid];
  const float y1 = (v1 - mean) * rstd * g[tid + 256] + b[tid + 256];
  const float y2 = (v2 - mean) * rstd * g[tid + 512] + b[tid + 512];
  float* of = outf + row * 768;
  bf16* ob = outb + row * 768;
  of[tid] = y0;        of[tid + 256] = y1;        of[tid + 512] = y2;
  ob[tid] = (bf16)y0;  ob[tid + 256] = (bf16)y1;  ob[tid + 512] = (bf16)y2;
}

// ---------------------------------------------------------------------------
extern "C" void kernel_launch(void* const* d_in, const int* in_sizes, int n_in,
                              void* d_out, int out_size, void* d_ws, size_t ws_size,
                              hipStream_t stream)
{
  const float* x   = (const float*)d_in[0];
  const float* Wq  = (const float*)d_in[1];
  const float* bq  = (const float*)d_in[2];
  const float* Wk  = (const float*)d_in[3];
  const float* bk  = (const float*)d_in[4];
  const float* Wv  = (const float*)d_in[5];
  const float* bv  = (const float*)d_in[6];
  const float* Wo  = (const float*)d_in[7];
  const float* bo  = (const float*)d_in[8];
  const float* g1  = (const float*)d_in[9];
  const float* be1 = (const float*)d_in[10];
  const float* W2  = (const float*)d_in[11];
  const float* b2  = (const float*)d_in[12];
  const float* g2  = (const float*)d_in[13];
  const float* be2 = (const float*)d_in[14];
  (void)in_sizes; (void)n_in; (void)out_size; (void)ws_size;

  char* ws = (char*)d_ws;
  size_t off = 0;
  auto alloc = [&](size_t bytes) {
    void* p = ws + off;
    off = (off + bytes + 255) & ~(size_t)255;
    return p;
  };
  bf16*  wTqkv = (bf16*)alloc(12L * 2304 * 768 * 2);
  bf16*  wTo   = (bf16*)alloc(12L * 768 * 768 * 2);
  bf16*  wT2   = (bf16*)alloc(12L * 768 * 768 * 2);
  float* bqkv  = (float*)alloc(12L * 2304 * 4);
  float* xf    = (float*)alloc(4096L * 768 * 4);
  bf16*  xb    = (bf16*)alloc(4096L * 768 * 2);
  bf16*  qkv   = (bf16*)alloc(4096L * 2304 * 2);
  bf16*  vT    = (bf16*)alloc(96L * 64 * 512 * 2);
  bf16*  ctx   = (bf16*)alloc(4096L * 768 * 2);
  float* res1  = (float*)alloc(4096L * 768 * 4);
  float* out1f = (float*)alloc(4096L * 768 * 4);
  bf16*  out1b = (bf16*)alloc(4096L * 768 * 2);
  bf16*  h1b   = (bf16*)alloc(4096L * 768 * 2);
  float* res2  = (float*)alloc(4096L * 768 * 4);

  wprep<<<dim3(12, 12, 60), 256, 0, stream>>>(Wq, Wk, Wv, Wo, W2, wTqkv, wTo, wT2);
  bias_concat<<<dim3(108), 256, 0, stream>>>(bq, bk, bv, bqkv);
  xconv<<<dim3(12288), 256, 0, stream>>>(x, xf, xb);

  for (int l = 0; l < 12; ++l) {
    const bf16* wq_l   = wTqkv + (long)l * 2304 * 768;
    const bf16* wo_l   = wTo + (long)l * 589824;
    const bf16* w2_l   = wT2 + (long)l * 589824;
    const float* bqk_l = bqkv + l * 2304;
    float* lnout = (l == 11) ? (float*)d_out : xf;

    // QKV: [4096,768] x [768,2304] -> qkv bf16 (+bias) + vT dual-store for V
    gemm_bt<128, 128, true, false, 0, true, true><<<dim3(18, 32, 1), 256, 0, stream>>>(
        xb, wq_l, qkv, bqk_l, nullptr, vT, 768, 768, 768, 2304,
        1, 0, 0, 0, 0, 0, 0, 1.f);
    // fused attention -> ctx [B,S,H] bf16
    fattn<<<dim3(8, 96), 512, 0, stream>>>(qkv, vT, ctx);
    // attn out projection + residual(xf fp32) -> res1 fp32
    gemm_bt<128, 64, true, false, 1, false, false><<<dim3(12, 32, 1), 256, 0, stream>>>(
        ctx, wo_l, res1, bo + l * 768, xf, nullptr, 768, 768, 768, 768,
        1, 0, 0, 0, 0, 0, 0, 1.f);
    layernorm_k<<<dim3(4096), 256, 0, stream>>>(res1, g1 + l * 768, be1 + l * 768, out1f, out1b);
    // FF1: relu(out1 @ W2 + b2) -> h1b bf16
    gemm_bt<128, 64, true, true, 0, true, false><<<dim3(12, 32, 1), 256, 0, stream>>>(
        out1b, w2_l, h1b, b2 + l * 768, nullptr, nullptr, 768, 768, 768, 768,
        1, 0, 0, 0, 0, 0, 0, 1.f);
    // FF2: out1(fp32) + relu(h @ W2 + b2) -> res2 fp32
    gemm_bt<128, 64, true, true, 1, false, false><<<dim3(12, 32, 1), 256, 0, stream>>>(
        h1b, w2_l, res2, b2 + l * 768, out1f, nullptr, 768, 768, 768, 768,
        1, 0, 0, 0, 0, 0, 0, 1.f);
    layernorm_k<<<dim3(4096), 256, 0, stream>>>(res2, g2 + l * 768, be2 + l * 768, lnout, xb);
  }
}

// Round 6
// 1710.125 us; speedup vs baseline: 1.3380x; 1.0103x over previous
//
#include <hip/hip_runtime.h>
#include <cstdint>

typedef __bf16 bf16;
typedef __attribute__((ext_vector_type(4))) __bf16 bf16x4;
typedef __attribute__((ext_vector_type(8))) __bf16 bf16x8;
typedef __attribute__((ext_vector_type(4))) float f32x4;
typedef __attribute__((ext_vector_type(2))) float f32x2;

// async 16B/lane global->LDS (dest = wave-uniform base + lane*16)
#define ASYNC16(gptr, lptr)                                                      \
  __builtin_amdgcn_global_load_lds(                                              \
      (const __attribute__((address_space(1))) unsigned int*)(gptr),             \
      (__attribute__((address_space(3))) unsigned int*)(lptr), 16, 0, 0)

// ---------------------------------------------------------------------------
// C[M,N] = A[M,K] * BT[N,K]^T (bf16 in, fp32 acc). BK=64 as 2 BK=32 sub-tiles.
// RESMODE: 0 none, 1 fp32 residual, 3 recompute-LN residual:
//   v += (res[idx]-mean[row])*rstd[row]*lng[col]+lnb[col].
// OUTB: bf16 store. VTOUT: QKV GEMM dual-stores V cols transposed to vt.
// ---------------------------------------------------------------------------
template <int BM, int BN, bool BIAS, bool RELU, int RESMODE, bool OUTB, bool VTOUT>
__global__ __launch_bounds__(256) void gemm_bt(
    const bf16* __restrict__ A, const bf16* __restrict__ B, void* __restrict__ C,
    const float* __restrict__ bias, const float* __restrict__ res,
    const f32x2* __restrict__ stats, const float* __restrict__ lng,
    const float* __restrict__ lnb, bf16* __restrict__ vt, int K,
    int lda, int ldb, int ldc, int bdiv, long sA1, long sA2, long sB1, long sB2,
    long sC1, long sC2, float scale)
{
  constexpr int FM = BM / 32, FN = BN / 32;
  constexpr int CALLS_A = BM / 64, CALLS_B = BN / 64;   // per 32-k sub-tile
  __shared__ __align__(16) bf16 As[2 * BM * 32];
  __shared__ __align__(16) bf16 Bs[2 * BN * 32];
  const int tid = threadIdx.x;
  const int wave = tid >> 6, lane = tid & 63;
  const int zb = blockIdx.z / bdiv, zh = blockIdx.z % bdiv;
  const bf16* Ab = A + zb * sA1 + zh * sA2 + (long)blockIdx.y * BM * lda;
  const bf16* Bb = B + zb * sB1 + zh * sB2 + (long)blockIdx.x * BN * ldb;
  const int rA = lane >> 2, kA = (lane & 3) * 8;   // 1KB chunk = 16 rows x 64B
  const int wm = wave >> 1, wn = wave & 1;
  const int mBase = wm * (BM / 2) + (lane & 15);
  const int nBase = wn * (BN / 2) + (lane & 15);
  const int kOff = (lane >> 4) * 8;

  f32x4 acc[FM][FN] = {};

  for (int k0 = 0; k0 < K; k0 += 64) {
#pragma unroll
    for (int hh = 0; hh < 2; ++hh) {
      const int kh = k0 + hh * 32;
#pragma unroll
      for (int c = 0; c < CALLS_A; ++c) {
        const int cb = (wave * CALLS_A + c) << 10;
        ASYNC16(Ab + (long)((cb >> 6) + rA) * lda + kh + kA,
                ((char*)As) + hh * (BM * 64) + cb);
      }
#pragma unroll
      for (int c = 0; c < CALLS_B; ++c) {
        const int cb = (wave * CALLS_B + c) << 10;
        ASYNC16(Bb + (long)((cb >> 6) + rA) * ldb + kh + kA,
                ((char*)Bs) + hh * (BN * 64) + cb);
      }
    }
    __syncthreads();
#pragma unroll
    for (int t = 0; t < 2; ++t) {
      const bf16* Asub = As + t * BM * 32;
      const bf16* Bsub = Bs + t * BN * 32;
      bf16x8 af[FM], bfr[FN];
#pragma unroll
      for (int i = 0; i < FM; ++i)
        af[i] = *(const bf16x8*)&Asub[(mBase + i * 16) * 32 + kOff];
#pragma unroll
      for (int j = 0; j < FN; ++j)
        bfr[j] = *(const bf16x8*)&Bsub[(nBase + j * 16) * 32 + kOff];
#pragma unroll
      for (int i = 0; i < FM; ++i)
#pragma unroll
        for (int j = 0; j < FN; ++j)
          acc[i][j] = __builtin_amdgcn_mfma_f32_16x16x32_bf16(af[i], bfr[j], acc[i][j], 0, 0, 0);
    }
    __syncthreads();
  }

  // C/D frag: col = lane&15, row = (lane>>4)*4 + r
  const long cBase = zb * sC1 + zh * sC2;
  const int rowB = blockIdx.y * BM + wm * (BM / 2) + ((lane >> 4) << 2);
  const int colB = blockIdx.x * BN + wn * (BN / 2) + (lane & 15);
#pragma unroll
  for (int i = 0; i < FM; ++i) {
    const int row0 = rowB + i * 16;
#pragma unroll
    for (int j = 0; j < FN; ++j) {
      const int col = colB + j * 16;
      float bv = 0.f;
      if constexpr (BIAS) bv = bias[col];
      float gv = 0.f, lv = 0.f;
      if constexpr (RESMODE == 3) { gv = lng[col]; lv = lnb[col]; }
      bf16x4 pk;
#pragma unroll
      for (int r = 0; r < 4; ++r) {
        const int row = row0 + r;
        float v = acc[i][j][r] * scale + bv;
        if constexpr (RELU) v = fmaxf(v, 0.f);
        const long idx = cBase + (long)row * ldc + col;
        if constexpr (RESMODE == 1) v += res[idx];
        if constexpr (RESMODE == 3) {
          const f32x2 st = stats[row];
          v += (res[idx] - st.x) * st.y * gv + lv;
        }
        if constexpr (OUTB) ((bf16*)C)[idx] = (bf16)v;
        else                ((float*)C)[idx] = v;
        if constexpr (VTOUT) pk[r] = (bf16)v;
      }
      if constexpr (VTOUT) {
        if (col >= 1536) {   // V columns: also store transposed
          const int cc = col - 1536;
          const int h = cc >> 6, d = cc & 63;
          const int b = row0 >> 9, s = row0 & 511;
          *(bf16x4*)&vt[(((long)(b * 12 + h) * 64 + d) << 9) + s] = pk;
        }
      }
    }
  }
}

// ---------------------------------------------------------------------------
// Fused attention, 512 threads (8 waves = 2 row-groups x 4 col-waves).
// ---------------------------------------------------------------------------
__global__ __launch_bounds__(512, 1) void fattn(
    const bf16* __restrict__ qkv, const bf16* __restrict__ vT,
    bf16* __restrict__ ctx)
{
  __shared__ __align__(16) bf16 Qs[64 * 64];      //  8 KB
  __shared__ __align__(16) bf16 KVs[512 * 64];    // 64 KB (K ph1, V ph3)
  __shared__ __align__(16) bf16 Ps[64 * 520];     // 65 KB
  __shared__ float sm[64 * 4];
  __shared__ float ssum[64 * 4];

  const int tid = threadIdx.x, wave = tid >> 6, lane = tid & 63;
  const int wg = wave >> 2, wc = wave & 3;
  const int bh = blockIdx.y;
  const int b = bh / 12, h = bh % 12;
  const int q0 = blockIdx.x * 64;
  const bf16* Qg = qkv + (long)(b * 512 + q0) * 2304 + h * 64;
  const bf16* Kg = qkv + (long)(b * 512) * 2304 + 768 + h * 64;
  const bf16* Vg = vT + (long)bh * 32768;

  const int rq = lane >> 3;                       // row within 1KB chunk
  const int kx = (((lane & 7) ^ rq) << 3);        // XOR-swizzled k-offset
  ASYNC16(Qg + (long)(wave * 8 + rq) * 2304 + kx, ((char*)Qs) + (wave << 10));
#pragma unroll
  for (int c = 0; c < 8; ++c) {                   // K: 64KB, 8 chunks/wave
    const int cb = (wave * 8 + c) << 10;
    ASYNC16(Kg + (long)((cb >> 7) + rq) * 2304 + kx, ((char*)KVs) + cb);
  }
  __syncthreads();

  const int m0 = lane & 15, q = lane >> 4;
  const int sw = (m0 & 7);                        // read-side swizzle key
  f32x4 acc[2][8] = {};
#pragma unroll
  for (int t = 0; t < 2; ++t) {
    const int ch = ((t * 4 + q) ^ sw) << 3;
    bf16x8 af[2];
#pragma unroll
    for (int i = 0; i < 2; ++i)
      af[i] = *(const bf16x8*)&Qs[(wg * 32 + i * 16 + m0) * 64 + ch];
#pragma unroll
    for (int j = 0; j < 8; ++j) {
      bf16x8 bf = *(const bf16x8*)&KVs[(wc * 128 + j * 16 + m0) * 64 + ch];
#pragma unroll
      for (int i = 0; i < 2; ++i)
        acc[i][j] = __builtin_amdgcn_mfma_f32_16x16x32_bf16(af[i], bf, acc[i][j], 0, 0, 0);
    }
  }

#pragma unroll
  for (int i = 0; i < 2; ++i)
#pragma unroll
    for (int r = 0; r < 4; ++r) {
      float m = acc[i][0][r];
#pragma unroll
      for (int j = 1; j < 8; ++j) m = fmaxf(m, acc[i][j][r]);
#pragma unroll
      for (int msk = 1; msk < 16; msk <<= 1) m = fmaxf(m, __shfl_xor(m, msk));
      if (m0 == 0) sm[(wg * 32 + i * 16 + q * 4 + r) * 4 + wc] = m;
    }
  __syncthreads();   // K reads done; sm visible

  {  // V loads into KVs (in flight during softmax)
#pragma unroll
    for (int c = 0; c < 8; ++c) {
      const int d = wave * 8 + c;
      const int cb = (wave * 8 + c) << 10;
      ASYNC16(Vg + (long)d * 512 + ((lane ^ c) << 3), ((char*)KVs) + cb);
    }
  }

  const float SCL = 0.125f;
#pragma unroll
  for (int i = 0; i < 2; ++i)
#pragma unroll
    for (int r = 0; r < 4; ++r) {
      const int row = wg * 32 + i * 16 + q * 4 + r;
      f32x4 mv = *(const f32x4*)&sm[row * 4];
      const float M = fmaxf(fmaxf(mv[0], mv[1]), fmaxf(mv[2], mv[3])) * SCL;
      float s = 0.f;
#pragma unroll
      for (int j = 0; j < 8; ++j) {
        const float p = __expf(acc[i][j][r] * SCL - M);
        s += p;
        Ps[row * 520 + wc * 128 + j * 16 + m0] = (bf16)p;
      }
#pragma unroll
      for (int msk = 1; msk < 16; msk <<= 1) s += __shfl_xor(s, msk);
      if (m0 == 0) ssum[row * 4 + wc] = s;
    }
  __syncthreads();   // drains V vmcnt + Ps/ssum writes

  f32x4 cacc[2] = {};
#pragma unroll
  for (int t = 0; t < 16; ++t) {
    const int ch = ((t * 4 + q) ^ sw) << 3;
    bf16x8 bf = *(const bf16x8*)&KVs[(wc * 16 + m0) * 512 + ch];
#pragma unroll
    for (int i = 0; i < 2; ++i) {
      bf16x8 af = *(const bf16x8*)&Ps[(wg * 32 + i * 16 + m0) * 520 + t * 32 + q * 8];
      cacc[i] = __builtin_amdgcn_mfma_f32_16x16x32_bf16(af, bf, cacc[i], 0, 0, 0);
    }
  }
  const long cbase = (long)(b * 512 + q0) * 768 + h * 64;
  const int col = wc * 16 + m0;
#pragma unroll
  for (int i = 0; i < 2; ++i)
#pragma unroll
    for (int r = 0; r < 4; ++r) {
      const int row = wg * 32 + i * 16 + q * 4 + r;
      f32x4 sv = *(const f32x4*)&ssum[row * 4];
      const float inv = 1.f / (sv[0] + sv[1] + sv[2] + sv[3]);
      ctx[cbase + (long)row * 768 + col] = (bf16)(cacc[i][r] * inv);
    }
}

// ---------------------------------------------------------------------------
// Slab weight prep: one block per (64-k slab, l*5+t). Reads 64 full rows of
// W[k][n] contiguously, packs k-pairs to u32, transposes via swizzled LDS,
// writes WT[n][k] bf16 in 128B runs.
// ---------------------------------------------------------------------------
static __device__ inline unsigned pk2(float lo, float hi) {
  const unsigned short a = __builtin_bit_cast(unsigned short, (bf16)lo);
  const unsigned short b = __builtin_bit_cast(unsigned short, (bf16)hi);
  return (unsigned)a | ((unsigned)b << 16);
}

__global__ __launch_bounds__(256) void wprep(
    const float* __restrict__ Wq, const float* __restrict__ Wk,
    const float* __restrict__ Wv, const float* __restrict__ Wo,
    const float* __restrict__ W2, bf16* __restrict__ Tqkv, bf16* __restrict__ To,
    bf16* __restrict__ T2)
{
  const int l = blockIdx.y / 5, t = blockIdx.y % 5;
  const int k0 = blockIdx.x * 64;
  const float* W = (t == 0) ? Wq : (t == 1) ? Wk : (t == 2) ? Wv : (t == 3) ? Wo : W2;
  W += (long)l * 589824;
  __shared__ unsigned Tl[768 * 34];   // [n][pair] u32 = (bf16 k=2p, k=2p+1), swizzled cols
  const int tid = threadIdx.x;

#pragma unroll
  for (int it = 0; it < 12; ++it) {
    const int idx = it * 256 + tid;
    const int g = idx % 96;          // 8-col group (fast in lanes -> coalesced)
    const int p = idx / 96;          // k-pair 0..31
    const float* src0 = W + (long)(k0 + 2 * p) * 768 + g * 8;
    const f32x4 a0 = *(const f32x4*)(src0);
    const f32x4 a1 = *(const f32x4*)(src0 + 4);
    const f32x4 b0 = *(const f32x4*)(src0 + 768);
    const f32x4 b1 = *(const f32x4*)(src0 + 772);
    const int pc = p ^ (4 * (g & 7));    // XOR swizzle (key = n>>3 & 7 = g&7)
    unsigned* rowp = &Tl[(8 * g) * 34];
#pragma unroll
    for (int c = 0; c < 4; ++c) {
      rowp[c * 34 + pc]       = pk2(a0[c], b0[c]);
      rowp[(c + 4) * 34 + pc] = pk2(a1[c], b1[c]);
    }
  }
  __syncthreads();

  bf16* dstBase;
  if (t < 3)       dstBase = Tqkv + (long)l * 2304 * 768 + (long)t * 768 * 768;
  else if (t == 3) dstBase = To + (long)l * 589824;
  else             dstBase = T2 + (long)l * 589824;

#pragma unroll
  for (int it = 0; it < 12; ++it) {
    const int n = it * 64 + (tid >> 2);
    const int q = tid & 3;
    const int key = 4 * ((n >> 3) & 7);
    const unsigned* row = &Tl[n * 34];
    unsigned o[8];
#pragma unroll
    for (int i = 0; i < 4; ++i) {
      const int col = (8 * q + 2 * i) ^ key;
      const uint2 u = *(const uint2*)&row[col];
      o[2 * i] = u.x; o[2 * i + 1] = u.y;
    }
    unsigned* d = (unsigned*)(dstBase + (long)n * 768 + k0) + q * 8;
    uint4 w0; w0.x = o[0]; w0.y = o[1]; w0.z = o[2]; w0.w = o[3];
    uint4 w1; w1.x = o[4]; w1.y = o[5]; w1.z = o[6]; w1.w = o[7];
    *(uint4*)d = w0;
    *(uint4*)(d + 4) = w1;
  }
}

__global__ void bias_concat(const float* __restrict__ bq, const float* __restrict__ bk,
                            const float* __restrict__ bv, float* __restrict__ o)
{
  const int i = blockIdx.x * 256 + threadIdx.x;
  if (i >= 12 * 2304) return;
  const int l = i / 2304, n = i % 2304;
  o[i] = (n < 768) ? bq[l * 768 + n] : (n < 1536) ? bk[l * 768 + n - 768] : bv[l * 768 + n - 1536];
}

__global__ void xconv(const float* __restrict__ x, bf16* __restrict__ xb)
{
  const long i = (long)blockIdx.x * 256 + threadIdx.x;
  xb[i] = (bf16)x[i];
}

// one block per 768-elem row; fp32 in -> bf16 out + per-row (mean,rstd) stats
// (+ optional fp32 out for the final layer)
__global__ __launch_bounds__(256) void layernorm_k(
    const float* __restrict__ in, const float* __restrict__ g,
    const float* __restrict__ b, bf16* __restrict__ outb,
    f32x2* __restrict__ stats, float* __restrict__ outf)
{
  const long row = blockIdx.x;
  const int tid = threadIdx.x;
  const float* xr = in + row * 768;
  const float v0 = xr[tid], v1 = xr[tid + 256], v2 = xr[tid + 512];
  float s = v0 + v1 + v2;
  float qv = v0 * v0 + v1 * v1 + v2 * v2;
#pragma unroll
  for (int o = 32; o > 0; o >>= 1) { s += __shfl_down(s, o); qv += __shfl_down(qv, o); }
  __shared__ float rs[4], rq[4];
  const int wave = tid >> 6, lane = tid & 63;
  if (lane == 0) { rs[wave] = s; rq[wave] = qv; }
  __syncthreads();
  const float st = rs[0] + rs[1] + rs[2] + rs[3];
  const float qt = rq[0] + rq[1] + rq[2] + rq[3];
  const float mean = st * (1.f / 768.f);
  float var = qt * (1.f / 768.f) - mean * mean;
  var = fmaxf(var, 0.f);
  const float rstd = rsqrtf(var + 1e-12f);
  if (tid == 0) { f32x2 sv; sv.x = mean; sv.y = rstd; stats[row] = sv; }
  const float y0 = (v0 - mean) * rstd * g[tid] + b[tid];
  const float y1 = (v1 - mean) * rstd * g[tid + 256] + b[tid + 256];
  const float y2 = (v2 - mean) * rstd * g[tid + 512] + b[tid + 512];
  bf16* ob = outb + row * 768;
  ob[tid] = (bf16)y0; ob[tid + 256] = (bf16)y1; ob[tid + 512] = (bf16)y2;
  if (outf) {
    float* of = outf + row * 768;
    of[tid] = y0; of[tid + 256] = y1; of[tid + 512] = y2;
  }
}

// ---------------------------------------------------------------------------
extern "C" void kernel_launch(void* const* d_in, const int* in_sizes, int n_in,
                              void* d_out, int out_size, void* d_ws, size_t ws_size,
                              hipStream_t stream)
{
  const float* x   = (const float*)d_in[0];
  const float* Wq  = (const float*)d_in[1];
  const float* bq  = (const float*)d_in[2];
  const float* Wk  = (const float*)d_in[3];
  const float* bk  = (const float*)d_in[4];
  const float* Wv  = (const float*)d_in[5];
  const float* bv  = (const float*)d_in[6];
  const float* Wo  = (const float*)d_in[7];
  const float* bo  = (const float*)d_in[8];
  const float* g1  = (const float*)d_in[9];
  const float* be1 = (const float*)d_in[10];
  const float* W2  = (const float*)d_in[11];
  const float* b2  = (const float*)d_in[12];
  const float* g2  = (const float*)d_in[13];
  const float* be2 = (const float*)d_in[14];
  (void)in_sizes; (void)n_in; (void)out_size; (void)ws_size;

  char* ws = (char*)d_ws;
  size_t off = 0;
  auto alloc = [&](size_t bytes) {
    void* p = ws + off;
    off = (off + bytes + 255) & ~(size_t)255;
    return p;
  };
  bf16*  wTqkv  = (bf16*)alloc(12L * 2304 * 768 * 2);
  bf16*  wTo    = (bf16*)alloc(12L * 768 * 768 * 2);
  bf16*  wT2    = (bf16*)alloc(12L * 768 * 768 * 2);
  float* bqkv   = (float*)alloc(12L * 2304 * 4);
  bf16*  xb     = (bf16*)alloc(4096L * 768 * 2);
  bf16*  qkv    = (bf16*)alloc(4096L * 2304 * 2);
  bf16*  vT     = (bf16*)alloc(96L * 64 * 512 * 2);
  bf16*  ctx    = (bf16*)alloc(4096L * 768 * 2);
  float* res1   = (float*)alloc(4096L * 768 * 4);
  bf16*  out1b  = (bf16*)alloc(4096L * 768 * 2);
  bf16*  h1b    = (bf16*)alloc(4096L * 768 * 2);
  float* res2   = (float*)alloc(4096L * 768 * 4);
  f32x2* stats1 = (f32x2*)alloc(4096L * 8);
  f32x2* stats2 = (f32x2*)alloc(4096L * 8);

  wprep<<<dim3(12, 60), 256, 0, stream>>>(Wq, Wk, Wv, Wo, W2, wTqkv, wTo, wT2);
  bias_concat<<<dim3(108), 256, 0, stream>>>(bq, bk, bv, bqkv);
  xconv<<<dim3(12288), 256, 0, stream>>>(x, xb);

  for (int l = 0; l < 12; ++l) {
    const bf16* wq_l   = wTqkv + (long)l * 2304 * 768;
    const bf16* wo_l   = wTo + (long)l * 589824;
    const bf16* w2_l   = wT2 + (long)l * 589824;
    const float* bqk_l = bqkv + l * 2304;

    // QKV: [4096,768] x [768,2304] -> qkv bf16 (+bias) + vT dual-store for V
    gemm_bt<128, 128, true, false, 0, true, true><<<dim3(18, 32, 1), 256, 0, stream>>>(
        xb, wq_l, qkv, bqk_l, nullptr, nullptr, nullptr, nullptr, vT, 768,
        768, 768, 2304, 1, 0, 0, 0, 0, 0, 0, 1.f);
    // fused attention -> ctx [B,S,H] bf16
    fattn<<<dim3(8, 96), 512, 0, stream>>>(qkv, vT, ctx);
    // attn out projection + residual -> res1 fp32
    if (l == 0) {
      gemm_bt<128, 64, true, false, 1, false, false><<<dim3(12, 32, 1), 256, 0, stream>>>(
          ctx, wo_l, res1, bo, x, nullptr, nullptr, nullptr, nullptr, 768,
          768, 768, 768, 1, 0, 0, 0, 0, 0, 0, 1.f);
    } else {
      gemm_bt<128, 64, true, false, 3, false, false><<<dim3(12, 32, 1), 256, 0, stream>>>(
          ctx, wo_l, res1, bo + l * 768, res2, stats2,
          g2 + (l - 1) * 768, be2 + (l - 1) * 768, nullptr, 768,
          768, 768, 768, 1, 0, 0, 0, 0, 0, 0, 1.f);
    }
    layernorm_k<<<dim3(4096), 256, 0, stream>>>(res1, g1 + l * 768, be1 + l * 768,
                                                out1b, stats1, nullptr);
    // FF1: relu(out1 @ W2 + b2) -> h1b bf16
    gemm_bt<128, 64, true, true, 0, true, false><<<dim3(12, 32, 1), 256, 0, stream>>>(
        out1b, w2_l, h1b, b2 + l * 768, nullptr, nullptr, nullptr, nullptr, nullptr, 768,
        768, 768, 768, 1, 0, 0, 0, 0, 0, 0, 1.f);
    // FF2: LN1(res1) + relu(h @ W2 + b2) -> res2 fp32
    gemm_bt<128, 64, true, true, 3, false, false><<<dim3(12, 32, 1), 256, 0, stream>>>(
        h1b, w2_l, res2, b2 + l * 768, res1, stats1,
        g1 + l * 768, be1 + l * 768, nullptr, 768,
        768, 768, 768, 1, 0, 0, 0, 0, 0, 0, 1.f);
    layernorm_k<<<dim3(4096), 256, 0, stream>>>(res2, g2 + l * 768, be2 + l * 768,
                                                xb, stats2, (l == 11) ? (float*)d_out : nullptr);
  }
}

// Round 7
// 1635.184 us; speedup vs baseline: 1.3994x; 1.0458x over previous
//
#include <hip/hip_runtime.h>
#include <cstdint>

typedef __bf16 bf16;
typedef __attribute__((ext_vector_type(4))) __bf16 bf16x4;
typedef __attribute__((ext_vector_type(8))) __bf16 bf16x8;
typedef __attribute__((ext_vector_type(4))) float f32x4;
typedef __attribute__((ext_vector_type(2))) float f32x2;

// async 16B/lane global->LDS (dest = wave-uniform base + lane*16)
#define ASYNC16(gptr, lptr)                                                      \
  __builtin_amdgcn_global_load_lds(                                              \
      (const __attribute__((address_space(1))) unsigned int*)(gptr),             \
      (__attribute__((address_space(3))) unsigned int*)(lptr), 16, 0, 0)

// ---------------------------------------------------------------------------
// C[M,N] = A[M,K] * BT[N,K]^T (bf16 in, fp32 acc). BK=64 as 2 BK=32 sub-tiles.
// RESMODE: 0 none, 1 fp32 residual, 3 recompute-LN residual:
//   v += (res[idx]-mean[row])*rstd[row]*lng[col]+lnb[col].
// OUTB: bf16 store. VTOUT: QKV GEMM dual-stores V cols transposed to vt.
// 64x64 tiles + MINW=6: 16KB LDS -> 6 blocks/CU co-resident; small-K GEMMs
// here are tail/occupancy-bound, not staging-bound.
// ---------------------------------------------------------------------------
template <int BM, int BN, bool BIAS, bool RELU, int RESMODE, bool OUTB, bool VTOUT, int MINW>
__global__ __launch_bounds__(256, MINW) void gemm_bt(
    const bf16* __restrict__ A, const bf16* __restrict__ B, void* __restrict__ C,
    const float* __restrict__ bias, const float* __restrict__ res,
    const f32x2* __restrict__ stats, const float* __restrict__ lng,
    const float* __restrict__ lnb, bf16* __restrict__ vt, int K,
    int lda, int ldb, int ldc, int bdiv, long sA1, long sA2, long sB1, long sB2,
    long sC1, long sC2, float scale)
{
  constexpr int FM = BM / 32, FN = BN / 32;
  constexpr int CALLS_A = BM / 64, CALLS_B = BN / 64;   // per 32-k sub-tile
  __shared__ __align__(16) bf16 As[2 * BM * 32];
  __shared__ __align__(16) bf16 Bs[2 * BN * 32];
  const int tid = threadIdx.x;
  const int wave = tid >> 6, lane = tid & 63;
  const int zb = blockIdx.z / bdiv, zh = blockIdx.z % bdiv;
  const bf16* Ab = A + zb * sA1 + zh * sA2 + (long)blockIdx.y * BM * lda;
  const bf16* Bb = B + zb * sB1 + zh * sB2 + (long)blockIdx.x * BN * ldb;
  const int rA = lane >> 2, kA = (lane & 3) * 8;   // 1KB chunk = 16 rows x 64B
  const int wm = wave >> 1, wn = wave & 1;
  const int mBase = wm * (BM / 2) + (lane & 15);
  const int nBase = wn * (BN / 2) + (lane & 15);
  const int kOff = (lane >> 4) * 8;

  f32x4 acc[FM][FN] = {};

  for (int k0 = 0; k0 < K; k0 += 64) {
#pragma unroll
    for (int hh = 0; hh < 2; ++hh) {
      const int kh = k0 + hh * 32;
#pragma unroll
      for (int c = 0; c < CALLS_A; ++c) {
        const int cb = (wave * CALLS_A + c) << 10;
        ASYNC16(Ab + (long)((cb >> 6) + rA) * lda + kh + kA,
                ((char*)As) + hh * (BM * 64) + cb);
      }
#pragma unroll
      for (int c = 0; c < CALLS_B; ++c) {
        const int cb = (wave * CALLS_B + c) << 10;
        ASYNC16(Bb + (long)((cb >> 6) + rA) * ldb + kh + kA,
                ((char*)Bs) + hh * (BN * 64) + cb);
      }
    }
    __syncthreads();
#pragma unroll
    for (int t = 0; t < 2; ++t) {
      const bf16* Asub = As + t * BM * 32;
      const bf16* Bsub = Bs + t * BN * 32;
      bf16x8 af[FM], bfr[FN];
#pragma unroll
      for (int i = 0; i < FM; ++i)
        af[i] = *(const bf16x8*)&Asub[(mBase + i * 16) * 32 + kOff];
#pragma unroll
      for (int j = 0; j < FN; ++j)
        bfr[j] = *(const bf16x8*)&Bsub[(nBase + j * 16) * 32 + kOff];
#pragma unroll
      for (int i = 0; i < FM; ++i)
#pragma unroll
        for (int j = 0; j < FN; ++j)
          acc[i][j] = __builtin_amdgcn_mfma_f32_16x16x32_bf16(af[i], bfr[j], acc[i][j], 0, 0, 0);
    }
    __syncthreads();
  }

  // C/D frag: col = lane&15, row = (lane>>4)*4 + r
  const long cBase = zb * sC1 + zh * sC2;
  const int rowB = blockIdx.y * BM + wm * (BM / 2) + ((lane >> 4) << 2);
  const int colB = blockIdx.x * BN + wn * (BN / 2) + (lane & 15);
#pragma unroll
  for (int i = 0; i < FM; ++i) {
    const int row0 = rowB + i * 16;
#pragma unroll
    for (int j = 0; j < FN; ++j) {
      const int col = colB + j * 16;
      float bv = 0.f;
      if constexpr (BIAS) bv = bias[col];
      float gv = 0.f, lv = 0.f;
      if constexpr (RESMODE == 3) { gv = lng[col]; lv = lnb[col]; }
      bf16x4 pk;
#pragma unroll
      for (int r = 0; r < 4; ++r) {
        const int row = row0 + r;
        float v = acc[i][j][r] * scale + bv;
        if constexpr (RELU) v = fmaxf(v, 0.f);
        const long idx = cBase + (long)row * ldc + col;
        if constexpr (RESMODE == 1) v += res[idx];
        if constexpr (RESMODE == 3) {
          const f32x2 st = stats[row];
          v += (res[idx] - st.x) * st.y * gv + lv;
        }
        if constexpr (OUTB) ((bf16*)C)[idx] = (bf16)v;
        else                ((float*)C)[idx] = v;
        if constexpr (VTOUT) pk[r] = (bf16)v;
      }
      if constexpr (VTOUT) {
        if (col >= 1536) {   // V columns: also store transposed
          const int cc = col - 1536;
          const int h = cc >> 6, d = cc & 63;
          const int b = row0 >> 9, s = row0 & 511;
          *(bf16x4*)&vt[(((long)(b * 12 + h) * 64 + d) << 9) + s] = pk;
        }
      }
    }
  }
}

// ---------------------------------------------------------------------------
// Fused attention, 512 threads (8 waves = 2 row-groups x 4 col-waves).
// ---------------------------------------------------------------------------
__global__ __launch_bounds__(512, 1) void fattn(
    const bf16* __restrict__ qkv, const bf16* __restrict__ vT,
    bf16* __restrict__ ctx)
{
  __shared__ __align__(16) bf16 Qs[64 * 64];      //  8 KB
  __shared__ __align__(16) bf16 KVs[512 * 64];    // 64 KB (K ph1, V ph3)
  __shared__ __align__(16) bf16 Ps[64 * 520];     // 65 KB
  __shared__ float sm[64 * 4];
  __shared__ float ssum[64 * 4];

  const int tid = threadIdx.x, wave = tid >> 6, lane = tid & 63;
  const int wg = wave >> 2, wc = wave & 3;
  const int bh = blockIdx.y;
  const int b = bh / 12, h = bh % 12;
  const int q0 = blockIdx.x * 64;
  const bf16* Qg = qkv + (long)(b * 512 + q0) * 2304 + h * 64;
  const bf16* Kg = qkv + (long)(b * 512) * 2304 + 768 + h * 64;
  const bf16* Vg = vT + (long)bh * 32768;

  const int rq = lane >> 3;                       // row within 1KB chunk
  const int kx = (((lane & 7) ^ rq) << 3);        // XOR-swizzled k-offset
  ASYNC16(Qg + (long)(wave * 8 + rq) * 2304 + kx, ((char*)Qs) + (wave << 10));
#pragma unroll
  for (int c = 0; c < 8; ++c) {                   // K: 64KB, 8 chunks/wave
    const int cb = (wave * 8 + c) << 10;
    ASYNC16(Kg + (long)((cb >> 7) + rq) * 2304 + kx, ((char*)KVs) + cb);
  }
  __syncthreads();

  const int m0 = lane & 15, q = lane >> 4;
  const int sw = (m0 & 7);                        // read-side swizzle key
  f32x4 acc[2][8] = {};
#pragma unroll
  for (int t = 0; t < 2; ++t) {
    const int ch = ((t * 4 + q) ^ sw) << 3;
    bf16x8 af[2];
#pragma unroll
    for (int i = 0; i < 2; ++i)
      af[i] = *(const bf16x8*)&Qs[(wg * 32 + i * 16 + m0) * 64 + ch];
#pragma unroll
    for (int j = 0; j < 8; ++j) {
      bf16x8 bf = *(const bf16x8*)&KVs[(wc * 128 + j * 16 + m0) * 64 + ch];
#pragma unroll
      for (int i = 0; i < 2; ++i)
        acc[i][j] = __builtin_amdgcn_mfma_f32_16x16x32_bf16(af[i], bf, acc[i][j], 0, 0, 0);
    }
  }

#pragma unroll
  for (int i = 0; i < 2; ++i)
#pragma unroll
    for (int r = 0; r < 4; ++r) {
      float m = acc[i][0][r];
#pragma unroll
      for (int j = 1; j < 8; ++j) m = fmaxf(m, acc[i][j][r]);
#pragma unroll
      for (int msk = 1; msk < 16; msk <<= 1) m = fmaxf(m, __shfl_xor(m, msk));
      if (m0 == 0) sm[(wg * 32 + i * 16 + q * 4 + r) * 4 + wc] = m;
    }
  __syncthreads();   // K reads done; sm visible

  {  // V loads into KVs (in flight during softmax)
#pragma unroll
    for (int c = 0; c < 8; ++c) {
      const int d = wave * 8 + c;
      const int cb = (wave * 8 + c) << 10;
      ASYNC16(Vg + (long)d * 512 + ((lane ^ c) << 3), ((char*)KVs) + cb);
    }
  }

  const float SCL = 0.125f;
#pragma unroll
  for (int i = 0; i < 2; ++i)
#pragma unroll
    for (int r = 0; r < 4; ++r) {
      const int row = wg * 32 + i * 16 + q * 4 + r;
      f32x4 mv = *(const f32x4*)&sm[row * 4];
      const float M = fmaxf(fmaxf(mv[0], mv[1]), fmaxf(mv[2], mv[3])) * SCL;
      float s = 0.f;
#pragma unroll
      for (int j = 0; j < 8; ++j) {
        const float p = __expf(acc[i][j][r] * SCL - M);
        s += p;
        Ps[row * 520 + wc * 128 + j * 16 + m0] = (bf16)p;
      }
#pragma unroll
      for (int msk = 1; msk < 16; msk <<= 1) s += __shfl_xor(s, msk);
      if (m0 == 0) ssum[row * 4 + wc] = s;
    }
  __syncthreads();   // drains V vmcnt + Ps/ssum writes

  f32x4 cacc[2] = {};
#pragma unroll
  for (int t = 0; t < 16; ++t) {
    const int ch = ((t * 4 + q) ^ sw) << 3;
    bf16x8 bf = *(const bf16x8*)&KVs[(wc * 16 + m0) * 512 + ch];
#pragma unroll
    for (int i = 0; i < 2; ++i) {
      bf16x8 af = *(const bf16x8*)&Ps[(wg * 32 + i * 16 + m0) * 520 + t * 32 + q * 8];
      cacc[i] = __builtin_amdgcn_mfma_f32_16x16x32_bf16(af, bf, cacc[i], 0, 0, 0);
    }
  }
  const long cbase = (long)(b * 512 + q0) * 768 + h * 64;
  const int col = wc * 16 + m0;
#pragma unroll
  for (int i = 0; i < 2; ++i)
#pragma unroll
    for (int r = 0; r < 4; ++r) {
      const int row = wg * 32 + i * 16 + q * 4 + r;
      f32x4 sv = *(const f32x4*)&ssum[row * 4];
      const float inv = 1.f / (sv[0] + sv[1] + sv[2] + sv[3]);
      ctx[cbase + (long)row * 768 + col] = (bf16)(cacc[i][r] * inv);
    }
}

// ---------------------------------------------------------------------------
// Slab weight prep, split in n (384-col halves): LDS 52KB -> 3 blocks/CU.
// One block per (64-k slab, n-half, l*5+t).
// ---------------------------------------------------------------------------
static __device__ inline unsigned pk2(float lo, float hi) {
  const unsigned short a = __builtin_bit_cast(unsigned short, (bf16)lo);
  const unsigned short b = __builtin_bit_cast(unsigned short, (bf16)hi);
  return (unsigned)a | ((unsigned)b << 16);
}

__global__ __launch_bounds__(256) void wprep(
    const float* __restrict__ Wq, const float* __restrict__ Wk,
    const float* __restrict__ Wv, const float* __restrict__ Wo,
    const float* __restrict__ W2, bf16* __restrict__ Tqkv, bf16* __restrict__ To,
    bf16* __restrict__ T2)
{
  const int l = blockIdx.y / 5, t = blockIdx.y % 5;
  const int k0 = (blockIdx.x >> 1) * 64;
  const int n0 = (blockIdx.x & 1) * 384;
  const float* W = (t == 0) ? Wq : (t == 1) ? Wk : (t == 2) ? Wv : (t == 3) ? Wo : W2;
  W += (long)l * 589824;
  __shared__ unsigned Tl[384 * 34];   // [n_local][pair] u32, XOR-swizzled cols
  const int tid = threadIdx.x;

#pragma unroll
  for (int it = 0; it < 6; ++it) {
    const int idx = it * 256 + tid;
    const int g = idx % 48;          // 8-col group within this 384-half
    const int p = idx / 48;          // k-pair 0..31
    const float* src0 = W + (long)(k0 + 2 * p) * 768 + n0 + g * 8;
    const f32x4 a0 = *(const f32x4*)(src0);
    const f32x4 a1 = *(const f32x4*)(src0 + 4);
    const f32x4 b0 = *(const f32x4*)(src0 + 768);
    const f32x4 b1 = *(const f32x4*)(src0 + 772);
    const int pc = p ^ (4 * (g & 7));    // XOR swizzle (key = (n_local>>3)&7)
    unsigned* rowp = &Tl[(8 * g) * 34];
#pragma unroll
    for (int c = 0; c < 4; ++c) {
      rowp[c * 34 + pc]       = pk2(a0[c], b0[c]);
      rowp[(c + 4) * 34 + pc] = pk2(a1[c], b1[c]);
    }
  }
  __syncthreads();

  bf16* dstBase;
  if (t < 3)       dstBase = Tqkv + (long)l * 2304 * 768 + (long)t * 768 * 768;
  else if (t == 3) dstBase = To + (long)l * 589824;
  else             dstBase = T2 + (long)l * 589824;

#pragma unroll
  for (int it = 0; it < 6; ++it) {
    const int nl = it * 64 + (tid >> 2);   // 0..383
    const int q = tid & 3;
    const int key = 4 * ((nl >> 3) & 7);
    const unsigned* row = &Tl[nl * 34];
    unsigned o[8];
#pragma unroll
    for (int i = 0; i < 4; ++i) {
      const int col = (8 * q + 2 * i) ^ key;
      const uint2 u = *(const uint2*)&row[col];
      o[2 * i] = u.x; o[2 * i + 1] = u.y;
    }
    unsigned* d = (unsigned*)(dstBase + (long)(n0 + nl) * 768 + k0) + q * 8;
    uint4 w0; w0.x = o[0]; w0.y = o[1]; w0.z = o[2]; w0.w = o[3];
    uint4 w1; w1.x = o[4]; w1.y = o[5]; w1.z = o[6]; w1.w = o[7];
    *(uint4*)d = w0;
    *(uint4*)(d + 4) = w1;
  }
}

__global__ void bias_concat(const float* __restrict__ bq, const float* __restrict__ bk,
                            const float* __restrict__ bv, float* __restrict__ o)
{
  const int i = blockIdx.x * 256 + threadIdx.x;
  if (i >= 12 * 2304) return;
  const int l = i / 2304, n = i % 2304;
  o[i] = (n < 768) ? bq[l * 768 + n] : (n < 1536) ? bk[l * 768 + n - 768] : bv[l * 768 + n - 1536];
}

__global__ void xconv(const float* __restrict__ x, bf16* __restrict__ xb)
{
  const long i = (long)blockIdx.x * 256 + threadIdx.x;
  xb[i] = (bf16)x[i];
}

// one block per 768-elem row; fp32 in -> bf16 out + per-row (mean,rstd) stats
// (+ optional fp32 out for the final layer)
__global__ __launch_bounds__(256) void layernorm_k(
    const float* __restrict__ in, const float* __restrict__ g,
    const float* __restrict__ b, bf16* __restrict__ outb,
    f32x2* __restrict__ stats, float* __restrict__ outf)
{
  const long row = blockIdx.x;
  const int tid = threadIdx.x;
  const float* xr = in + row * 768;
  const float v0 = xr[tid], v1 = xr[tid + 256], v2 = xr[tid + 512];
  float s = v0 + v1 + v2;
  float qv = v0 * v0 + v1 * v1 + v2 * v2;
#pragma unroll
  for (int o = 32; o > 0; o >>= 1) { s += __shfl_down(s, o); qv += __shfl_down(qv, o); }
  __shared__ float rs[4], rq[4];
  const int wave = tid >> 6, lane = tid & 63;
  if (lane == 0) { rs[wave] = s; rq[wave] = qv; }
  __syncthreads();
  const float st = rs[0] + rs[1] + rs[2] + rs[3];
  const float qt = rq[0] + rq[1] + rq[2] + rq[3];
  const float mean = st * (1.f / 768.f);
  float var = qt * (1.f / 768.f) - mean * mean;
  var = fmaxf(var, 0.f);
  const float rstd = rsqrtf(var + 1e-12f);
  if (tid == 0) { f32x2 sv; sv.x = mean; sv.y = rstd; stats[row] = sv; }
  const float y0 = (v0 - mean) * rstd * g[tid] + b[tid];
  const float y1 = (v1 - mean) * rstd * g[tid + 256] + b[tid + 256];
  const float y2 = (v2 - mean) * rstd * g[tid + 512] + b[tid + 512];
  bf16* ob = outb + row * 768;
  ob[tid] = (bf16)y0; ob[tid + 256] = (bf16)y1; ob[tid + 512] = (bf16)y2;
  if (outf) {
    float* of = outf + row * 768;
    of[tid] = y0; of[tid + 256] = y1; of[tid + 512] = y2;
  }
}

// ---------------------------------------------------------------------------
extern "C" void kernel_launch(void* const* d_in, const int* in_sizes, int n_in,
                              void* d_out, int out_size, void* d_ws, size_t ws_size,
                              hipStream_t stream)
{
  const float* x   = (const float*)d_in[0];
  const float* Wq  = (const float*)d_in[1];
  const float* bq  = (const float*)d_in[2];
  const float* Wk  = (const float*)d_in[3];
  const float* bk  = (const float*)d_in[4];
  const float* Wv  = (const float*)d_in[5];
  const float* bv  = (const float*)d_in[6];
  const float* Wo  = (const float*)d_in[7];
  const float* bo  = (const float*)d_in[8];
  const float* g1  = (const float*)d_in[9];
  const float* be1 = (const float*)d_in[10];
  const float* W2  = (const float*)d_in[11];
  const float* b2  = (const float*)d_in[12];
  const float* g2  = (const float*)d_in[13];
  const float* be2 = (const float*)d_in[14];
  (void)in_sizes; (void)n_in; (void)out_size; (void)ws_size;

  char* ws = (char*)d_ws;
  size_t off = 0;
  auto alloc = [&](size_t bytes) {
    void* p = ws + off;
    off = (off + bytes + 255) & ~(size_t)255;
    return p;
  };
  bf16*  wTqkv  = (bf16*)alloc(12L * 2304 * 768 * 2);
  bf16*  wTo    = (bf16*)alloc(12L * 768 * 768 * 2);
  bf16*  wT2    = (bf16*)alloc(12L * 768 * 768 * 2);
  float* bqkv   = (float*)alloc(12L * 2304 * 4);
  bf16*  xb     = (bf16*)alloc(4096L * 768 * 2);
  bf16*  qkv    = (bf16*)alloc(4096L * 2304 * 2);
  bf16*  vT     = (bf16*)alloc(96L * 64 * 512 * 2);
  bf16*  ctx    = (bf16*)alloc(4096L * 768 * 2);
  float* res1   = (float*)alloc(4096L * 768 * 4);
  bf16*  out1b  = (bf16*)alloc(4096L * 768 * 2);
  bf16*  h1b    = (bf16*)alloc(4096L * 768 * 2);
  float* res2   = (float*)alloc(4096L * 768 * 4);
  f32x2* stats1 = (f32x2*)alloc(4096L * 8);
  f32x2* stats2 = (f32x2*)alloc(4096L * 8);

  wprep<<<dim3(24, 60), 256, 0, stream>>>(Wq, Wk, Wv, Wo, W2, wTqkv, wTo, wT2);
  bias_concat<<<dim3(108), 256, 0, stream>>>(bq, bk, bv, bqkv);
  xconv<<<dim3(12288), 256, 0, stream>>>(x, xb);

  for (int l = 0; l < 12; ++l) {
    const bf16* wq_l   = wTqkv + (long)l * 2304 * 768;
    const bf16* wo_l   = wTo + (long)l * 589824;
    const bf16* w2_l   = wT2 + (long)l * 589824;
    const float* bqk_l = bqkv + l * 2304;

    // QKV: [4096,768] x [768,2304] -> qkv bf16 (+bias) + vT dual-store for V
    gemm_bt<64, 64, true, false, 0, true, true, 6><<<dim3(36, 64, 1), 256, 0, stream>>>(
        xb, wq_l, qkv, bqk_l, nullptr, nullptr, nullptr, nullptr, vT, 768,
        768, 768, 2304, 1, 0, 0, 0, 0, 0, 0, 1.f);
    // fused attention -> ctx [B,S,H] bf16
    fattn<<<dim3(8, 96), 512, 0, stream>>>(qkv, vT, ctx);
    // attn out projection + residual -> res1 fp32
    if (l == 0) {
      gemm_bt<64, 64, true, false, 1, false, false, 6><<<dim3(12, 64, 1), 256, 0, stream>>>(
          ctx, wo_l, res1, bo, x, nullptr, nullptr, nullptr, nullptr, 768,
          768, 768, 768, 1, 0, 0, 0, 0, 0, 0, 1.f);
    } else {
      gemm_bt<64, 64, true, false, 3, false, false, 6><<<dim3(12, 64, 1), 256, 0, stream>>>(
          ctx, wo_l, res1, bo + l * 768, res2, stats2,
          g2 + (l - 1) * 768, be2 + (l - 1) * 768, nullptr, 768,
          768, 768, 768, 1, 0, 0, 0, 0, 0, 0, 1.f);
    }
    layernorm_k<<<dim3(4096), 256, 0, stream>>>(res1, g1 + l * 768, be1 + l * 768,
                                                out1b, stats1, nullptr);
    // FF1: relu(out1 @ W2 + b2) -> h1b bf16
    gemm_bt<64, 64, true, true, 0, true, false, 6><<<dim3(12, 64, 1), 256, 0, stream>>>(
        out1b, w2_l, h1b, b2 + l * 768, nullptr, nullptr, nullptr, nullptr, nullptr, 768,
        768, 768, 768, 1, 0, 0, 0, 0, 0, 0, 1.f);
    // FF2: LN1(res1) + relu(h @ W2 + b2) -> res2 fp32
    gemm_bt<64, 64, true, true, 3, false, false, 6><<<dim3(12, 64, 1), 256, 0, stream>>>(
        h1b, w2_l, res2, b2 + l * 768, res1, stats1,
        g1 + l * 768, be1 + l * 768, nullptr, 768,
        768, 768, 768, 1, 0, 0, 0, 0, 0, 0, 1.f);
    layernorm_k<<<dim3(4096), 256, 0, stream>>>(res2, g2 + l * 768, be2 + l * 768,
                                                xb, stats2, (l == 11) ? (float*)d_out : nullptr);
  }
}

// Round 8
// 1603.398 us; speedup vs baseline: 1.4271x; 1.0198x over previous
//
#include <hip/hip_runtime.h>
#include <cstdint>

typedef __bf16 bf16;
typedef __attribute__((ext_vector_type(4))) __bf16 bf16x4;
typedef __attribute__((ext_vector_type(8))) __bf16 bf16x8;
typedef __attribute__((ext_vector_type(4))) float f32x4;
typedef __attribute__((ext_vector_type(2))) float f32x2;

// async 16B/lane global->LDS (dest = wave-uniform base + lane*16)
#define ASYNC16(gptr, lptr)                                                      \
  __builtin_amdgcn_global_load_lds(                                              \
      (const __attribute__((address_space(1))) unsigned int*)(gptr),             \
      (__attribute__((address_space(3))) unsigned int*)(lptr), 16, 0, 0)

// ---------------------------------------------------------------------------
// C[M,N] = A[M,K] * BT[N,K]^T (bf16 in, fp32 acc). BK=64 as 2 BK=32 sub-tiles.
// RESMODE: 0 none, 1 fp32 residual, 3 recompute-LN residual:
//   v += (res[idx]-mean[row])*rstd[row]*lng[col]+lnb[col].
// OUTB: bf16 store. VTOUT: QKV GEMM dual-stores V cols transposed to vt.
// ---------------------------------------------------------------------------
template <int BM, int BN, bool BIAS, bool RELU, int RESMODE, bool OUTB, bool VTOUT, int MINW>
__global__ __launch_bounds__(256, MINW) void gemm_bt(
    const bf16* __restrict__ A, const bf16* __restrict__ B, void* __restrict__ C,
    const float* __restrict__ bias, const float* __restrict__ res,
    const f32x2* __restrict__ stats, const float* __restrict__ lng,
    const float* __restrict__ lnb, bf16* __restrict__ vt, int K,
    int lda, int ldb, int ldc, int bdiv, long sA1, long sA2, long sB1, long sB2,
    long sC1, long sC2, float scale)
{
  constexpr int FM = BM / 32, FN = BN / 32;
  constexpr int CALLS_A = BM / 64, CALLS_B = BN / 64;   // per 32-k sub-tile
  __shared__ __align__(16) bf16 As[2 * BM * 32];
  __shared__ __align__(16) bf16 Bs[2 * BN * 32];
  const int tid = threadIdx.x;
  const int wave = tid >> 6, lane = tid & 63;
  const int zb = blockIdx.z / bdiv, zh = blockIdx.z % bdiv;
  const bf16* Ab = A + zb * sA1 + zh * sA2 + (long)blockIdx.y * BM * lda;
  const bf16* Bb = B + zb * sB1 + zh * sB2 + (long)blockIdx.x * BN * ldb;
  const int rA = lane >> 2, kA = (lane & 3) * 8;   // 1KB chunk = 16 rows x 64B
  const int wm = wave >> 1, wn = wave & 1;
  const int mBase = wm * (BM / 2) + (lane & 15);
  const int nBase = wn * (BN / 2) + (lane & 15);
  const int kOff = (lane >> 4) * 8;

  f32x4 acc[FM][FN] = {};

  for (int k0 = 0; k0 < K; k0 += 64) {
#pragma unroll
    for (int hh = 0; hh < 2; ++hh) {
      const int kh = k0 + hh * 32;
#pragma unroll
      for (int c = 0; c < CALLS_A; ++c) {
        const int cb = (wave * CALLS_A + c) << 10;
        ASYNC16(Ab + (long)((cb >> 6) + rA) * lda + kh + kA,
                ((char*)As) + hh * (BM * 64) + cb);
      }
#pragma unroll
      for (int c = 0; c < CALLS_B; ++c) {
        const int cb = (wave * CALLS_B + c) << 10;
        ASYNC16(Bb + (long)((cb >> 6) + rA) * ldb + kh + kA,
                ((char*)Bs) + hh * (BN * 64) + cb);
      }
    }
    __syncthreads();
#pragma unroll
    for (int t = 0; t < 2; ++t) {
      const bf16* Asub = As + t * BM * 32;
      const bf16* Bsub = Bs + t * BN * 32;
      bf16x8 af[FM], bfr[FN];
#pragma unroll
      for (int i = 0; i < FM; ++i)
        af[i] = *(const bf16x8*)&Asub[(mBase + i * 16) * 32 + kOff];
#pragma unroll
      for (int j = 0; j < FN; ++j)
        bfr[j] = *(const bf16x8*)&Bsub[(nBase + j * 16) * 32 + kOff];
#pragma unroll
      for (int i = 0; i < FM; ++i)
#pragma unroll
        for (int j = 0; j < FN; ++j)
          acc[i][j] = __builtin_amdgcn_mfma_f32_16x16x32_bf16(af[i], bfr[j], acc[i][j], 0, 0, 0);
    }
    __syncthreads();
  }

  // C/D frag: col = lane&15, row = (lane>>4)*4 + r
  const long cBase = zb * sC1 + zh * sC2;
  const int rowB = blockIdx.y * BM + wm * (BM / 2) + ((lane >> 4) << 2);
  const int colB = blockIdx.x * BN + wn * (BN / 2) + (lane & 15);
#pragma unroll
  for (int i = 0; i < FM; ++i) {
    const int row0 = rowB + i * 16;
#pragma unroll
    for (int j = 0; j < FN; ++j) {
      const int col = colB + j * 16;
      float bv = 0.f;
      if constexpr (BIAS) bv = bias[col];
      float gv = 0.f, lv = 0.f;
      if constexpr (RESMODE == 3) { gv = lng[col]; lv = lnb[col]; }
      bf16x4 pk;
#pragma unroll
      for (int r = 0; r < 4; ++r) {
        const int row = row0 + r;
        float v = acc[i][j][r] * scale + bv;
        if constexpr (RELU) v = fmaxf(v, 0.f);
        const long idx = cBase + (long)row * ldc + col;
        if constexpr (RESMODE == 1) v += res[idx];
        if constexpr (RESMODE == 3) {
          const f32x2 st = stats[row];
          v += (res[idx] - st.x) * st.y * gv + lv;
        }
        if constexpr (OUTB) ((bf16*)C)[idx] = (bf16)v;
        else                ((float*)C)[idx] = v;
        if constexpr (VTOUT) pk[r] = (bf16)v;
      }
      if constexpr (VTOUT) {
        if (col >= 1536) {   // V columns: also store transposed
          const int cc = col - 1536;
          const int h = cc >> 6, d = cc & 63;
          const int b = row0 >> 9, s = row0 & 511;
          *(bf16x4*)&vt[(((long)(b * 12 + h) * 64 + d) << 9) + s] = pk;
        }
      }
    }
  }
}

// ---------------------------------------------------------------------------
// Fused attention, 512 threads (8 waves = 2 row-groups x 4 col-waves).
// ---------------------------------------------------------------------------
__global__ __launch_bounds__(512, 1) void fattn(
    const bf16* __restrict__ qkv, const bf16* __restrict__ vT,
    bf16* __restrict__ ctx)
{
  __shared__ __align__(16) bf16 Qs[64 * 64];      //  8 KB
  __shared__ __align__(16) bf16 KVs[512 * 64];    // 64 KB (K ph1, V ph3)
  __shared__ __align__(16) bf16 Ps[64 * 520];     // 65 KB
  __shared__ float sm[64 * 4];
  __shared__ float ssum[64 * 4];

  const int tid = threadIdx.x, wave = tid >> 6, lane = tid & 63;
  const int wg = wave >> 2, wc = wave & 3;
  const int bh = blockIdx.y;
  const int b = bh / 12, h = bh % 12;
  const int q0 = blockIdx.x * 64;
  const bf16* Qg = qkv + (long)(b * 512 + q0) * 2304 + h * 64;
  const bf16* Kg = qkv + (long)(b * 512) * 2304 + 768 + h * 64;
  const bf16* Vg = vT + (long)bh * 32768;

  const int rq = lane >> 3;                       // row within 1KB chunk
  const int kx = (((lane & 7) ^ rq) << 3);        // XOR-swizzled k-offset
  ASYNC16(Qg + (long)(wave * 8 + rq) * 2304 + kx, ((char*)Qs) + (wave << 10));
#pragma unroll
  for (int c = 0; c < 8; ++c) {                   // K: 64KB, 8 chunks/wave
    const int cb = (wave * 8 + c) << 10;
    ASYNC16(Kg + (long)((cb >> 7) + rq) * 2304 + kx, ((char*)KVs) + cb);
  }
  __syncthreads();

  const int m0 = lane & 15, q = lane >> 4;
  const int sw = (m0 & 7);                        // read-side swizzle key
  f32x4 acc[2][8] = {};
#pragma unroll
  for (int t = 0; t < 2; ++t) {
    const int ch = ((t * 4 + q) ^ sw) << 3;
    bf16x8 af[2];
#pragma unroll
    for (int i = 0; i < 2; ++i)
      af[i] = *(const bf16x8*)&Qs[(wg * 32 + i * 16 + m0) * 64 + ch];
#pragma unroll
    for (int j = 0; j < 8; ++j) {
      bf16x8 bf = *(const bf16x8*)&KVs[(wc * 128 + j * 16 + m0) * 64 + ch];
#pragma unroll
      for (int i = 0; i < 2; ++i)
        acc[i][j] = __builtin_amdgcn_mfma_f32_16x16x32_bf16(af[i], bf, acc[i][j], 0, 0, 0);
    }
  }

#pragma unroll
  for (int i = 0; i < 2; ++i)
#pragma unroll
    for (int r = 0; r < 4; ++r) {
      float m = acc[i][0][r];
#pragma unroll
      for (int j = 1; j < 8; ++j) m = fmaxf(m, acc[i][j][r]);
#pragma unroll
      for (int msk = 1; msk < 16; msk <<= 1) m = fmaxf(m, __shfl_xor(m, msk));
      if (m0 == 0) sm[(wg * 32 + i * 16 + q * 4 + r) * 4 + wc] = m;
    }
  __syncthreads();   // K reads done; sm visible

  {  // V loads into KVs (in flight during softmax)
#pragma unroll
    for (int c = 0; c < 8; ++c) {
      const int d = wave * 8 + c;
      const int cb = (wave * 8 + c) << 10;
      ASYNC16(Vg + (long)d * 512 + ((lane ^ c) << 3), ((char*)KVs) + cb);
    }
  }

  const float SCL = 0.125f;
#pragma unroll
  for (int i = 0; i < 2; ++i)
#pragma unroll
    for (int r = 0; r < 4; ++r) {
      const int row = wg * 32 + i * 16 + q * 4 + r;
      f32x4 mv = *(const f32x4*)&sm[row * 4];
      const float M = fmaxf(fmaxf(mv[0], mv[1]), fmaxf(mv[2], mv[3])) * SCL;
      float s = 0.f;
#pragma unroll
      for (int j = 0; j < 8; ++j) {
        const float p = __expf(acc[i][j][r] * SCL - M);
        s += p;
        Ps[row * 520 + wc * 128 + j * 16 + m0] = (bf16)p;
      }
#pragma unroll
      for (int msk = 1; msk < 16; msk <<= 1) s += __shfl_xor(s, msk);
      if (m0 == 0) ssum[row * 4 + wc] = s;
    }
  __syncthreads();   // drains V vmcnt + Ps/ssum writes

  f32x4 cacc[2] = {};
#pragma unroll
  for (int t = 0; t < 16; ++t) {
    const int ch = ((t * 4 + q) ^ sw) << 3;
    bf16x8 bf = *(const bf16x8*)&KVs[(wc * 16 + m0) * 512 + ch];
#pragma unroll
    for (int i = 0; i < 2; ++i) {
      bf16x8 af = *(const bf16x8*)&Ps[(wg * 32 + i * 16 + m0) * 520 + t * 32 + q * 8];
      cacc[i] = __builtin_amdgcn_mfma_f32_16x16x32_bf16(af, bf, cacc[i], 0, 0, 0);
    }
  }
  const long cbase = (long)(b * 512 + q0) * 768 + h * 64;
  const int col = wc * 16 + m0;
#pragma unroll
  for (int i = 0; i < 2; ++i)
#pragma unroll
    for (int r = 0; r < 4; ++r) {
      const int row = wg * 32 + i * 16 + q * 4 + r;
      f32x4 sv = *(const f32x4*)&ssum[row * 4];
      const float inv = 1.f / (sv[0] + sv[1] + sv[2] + sv[3]);
      ctx[cbase + (long)row * 768 + col] = (bf16)(cacc[i][r] * inv);
    }
}

// ---------------------------------------------------------------------------
// Register-transpose weight prep (no LDS, no barriers, no bank conflicts).
// Each lane: 8k x 8n micro-tile. Lane = nm*8+km so 8 consecutive lanes write
// one contiguous 128B run of WT; reads are 8x32B runs per quarter-wave.
// Grid: (k-tiles 12, n-tiles 3, l*5+t 60); block = 4 waves side-by-side in n.
// ---------------------------------------------------------------------------
__global__ __launch_bounds__(256) void wprep(
    const float* __restrict__ Wq, const float* __restrict__ Wk,
    const float* __restrict__ Wv, const float* __restrict__ Wo,
    const float* __restrict__ W2, bf16* __restrict__ Tqkv, bf16* __restrict__ To,
    bf16* __restrict__ T2)
{
  const int l = blockIdx.z / 5, t = blockIdx.z % 5;
  const float* W = (t == 0) ? Wq : (t == 1) ? Wk : (t == 2) ? Wv : (t == 3) ? Wo : W2;
  W += (long)l * 589824;
  const int lane = threadIdx.x & 63, wave = threadIdx.x >> 6;
  const int km = lane & 7, nm = lane >> 3;
  const int kk = blockIdx.x * 64 + km * 8;
  const int nn = blockIdx.y * 256 + wave * 64 + nm * 8;

  f32x4 a[8][2];
#pragma unroll
  for (int j = 0; j < 8; ++j) {
    const float* src = W + (long)(kk + j) * 768 + nn;
    a[j][0] = *(const f32x4*)src;
    a[j][1] = *(const f32x4*)(src + 4);
  }

  bf16* dstBase;
  if (t < 3)       dstBase = Tqkv + (long)l * 2304 * 768 + (long)t * 768 * 768;
  else if (t == 3) dstBase = To + (long)l * 589824;
  else             dstBase = T2 + (long)l * 589824;

#pragma unroll
  for (int r = 0; r < 8; ++r) {
    bf16x8 o;
#pragma unroll
    for (int j = 0; j < 8; ++j)
      o[j] = (bf16)(r < 4 ? a[j][0][r] : a[j][1][r - 4]);
    *(bf16x8*)&dstBase[(long)(nn + r) * 768 + kk] = o;
  }
}

__global__ void bias_concat(const float* __restrict__ bq, const float* __restrict__ bk,
                            const float* __restrict__ bv, float* __restrict__ o)
{
  const int i = blockIdx.x * 256 + threadIdx.x;
  if (i >= 12 * 2304) return;
  const int l = i / 2304, n = i % 2304;
  o[i] = (n < 768) ? bq[l * 768 + n] : (n < 1536) ? bk[l * 768 + n - 768] : bv[l * 768 + n - 1536];
}

__global__ void xconv(const float* __restrict__ x, bf16* __restrict__ xb)
{
  const long i = (long)blockIdx.x * 256 + threadIdx.x;
  xb[i] = (bf16)x[i];
}

// one block per 768-elem row; fp32 in -> bf16 out + per-row (mean,rstd) stats
// (+ optional fp32 out for the final layer)
__global__ __launch_bounds__(256) void layernorm_k(
    const float* __restrict__ in, const float* __restrict__ g,
    const float* __restrict__ b, bf16* __restrict__ outb,
    f32x2* __restrict__ stats, float* __restrict__ outf)
{
  const long row = blockIdx.x;
  const int tid = threadIdx.x;
  const float* xr = in + row * 768;
  const float v0 = xr[tid], v1 = xr[tid + 256], v2 = xr[tid + 512];
  float s = v0 + v1 + v2;
  float qv = v0 * v0 + v1 * v1 + v2 * v2;
#pragma unroll
  for (int o = 32; o > 0; o >>= 1) { s += __shfl_down(s, o); qv += __shfl_down(qv, o); }
  __shared__ float rs[4], rq[4];
  const int wave = tid >> 6, lane = tid & 63;
  if (lane == 0) { rs[wave] = s; rq[wave] = qv; }
  __syncthreads();
  const float st = rs[0] + rs[1] + rs[2] + rs[3];
  const float qt = rq[0] + rq[1] + rq[2] + rq[3];
  const float mean = st * (1.f / 768.f);
  float var = qt * (1.f / 768.f) - mean * mean;
  var = fmaxf(var, 0.f);
  const float rstd = rsqrtf(var + 1e-12f);
  if (tid == 0) { f32x2 sv; sv.x = mean; sv.y = rstd; stats[row] = sv; }
  const float y0 = (v0 - mean) * rstd * g[tid] + b[tid];
  const float y1 = (v1 - mean) * rstd * g[tid + 256] + b[tid + 256];
  const float y2 = (v2 - mean) * rstd * g[tid + 512] + b[tid + 512];
  bf16* ob = outb + row * 768;
  ob[tid] = (bf16)y0; ob[tid + 256] = (bf16)y1; ob[tid + 512] = (bf16)y2;
  if (outf) {
    float* of = outf + row * 768;
    of[tid] = y0; of[tid + 256] = y1; of[tid + 512] = y2;
  }
}

// ---------------------------------------------------------------------------
extern "C" void kernel_launch(void* const* d_in, const int* in_sizes, int n_in,
                              void* d_out, int out_size, void* d_ws, size_t ws_size,
                              hipStream_t stream)
{
  const float* x   = (const float*)d_in[0];
  const float* Wq  = (const float*)d_in[1];
  const float* bq  = (const float*)d_in[2];
  const float* Wk  = (const float*)d_in[3];
  const float* bk  = (const float*)d_in[4];
  const float* Wv  = (const float*)d_in[5];
  const float* bv  = (const float*)d_in[6];
  const float* Wo  = (const float*)d_in[7];
  const float* bo  = (const float*)d_in[8];
  const float* g1  = (const float*)d_in[9];
  const float* be1 = (const float*)d_in[10];
  const float* W2  = (const float*)d_in[11];
  const float* b2  = (const float*)d_in[12];
  const float* g2  = (const float*)d_in[13];
  const float* be2 = (const float*)d_in[14];
  (void)in_sizes; (void)n_in; (void)out_size; (void)ws_size;

  char* ws = (char*)d_ws;
  size_t off = 0;
  auto alloc = [&](size_t bytes) {
    void* p = ws + off;
    off = (off + bytes + 255) & ~(size_t)255;
    return p;
  };
  bf16*  wTqkv  = (bf16*)alloc(12L * 2304 * 768 * 2);
  bf16*  wTo    = (bf16*)alloc(12L * 768 * 768 * 2);
  bf16*  wT2    = (bf16*)alloc(12L * 768 * 768 * 2);
  float* bqkv   = (float*)alloc(12L * 2304 * 4);
  bf16*  xb     = (bf16*)alloc(4096L * 768 * 2);
  bf16*  qkv    = (bf16*)alloc(4096L * 2304 * 2);
  bf16*  vT     = (bf16*)alloc(96L * 64 * 512 * 2);
  bf16*  ctx    = (bf16*)alloc(4096L * 768 * 2);
  float* res1   = (float*)alloc(4096L * 768 * 4);
  bf16*  out1b  = (bf16*)alloc(4096L * 768 * 2);
  bf16*  h1b    = (bf16*)alloc(4096L * 768 * 2);
  float* res2   = (float*)alloc(4096L * 768 * 4);
  f32x2* stats1 = (f32x2*)alloc(4096L * 8);
  f32x2* stats2 = (f32x2*)alloc(4096L * 8);

  wprep<<<dim3(12, 3, 60), 256, 0, stream>>>(Wq, Wk, Wv, Wo, W2, wTqkv, wTo, wT2);
  bias_concat<<<dim3(108), 256, 0, stream>>>(bq, bk, bv, bqkv);
  xconv<<<dim3(12288), 256, 0, stream>>>(x, xb);

  for (int l = 0; l < 12; ++l) {
    const bf16* wq_l   = wTqkv + (long)l * 2304 * 768;
    const bf16* wo_l   = wTo + (long)l * 589824;
    const bf16* w2_l   = wT2 + (long)l * 589824;
    const float* bqk_l = bqkv + l * 2304;

    // QKV: [4096,768] x [768,2304] -> qkv bf16 (+bias) + vT dual-store for V
    gemm_bt<128, 64, true, false, 0, true, true, 5><<<dim3(36, 32, 1), 256, 0, stream>>>(
        xb, wq_l, qkv, bqk_l, nullptr, nullptr, nullptr, nullptr, vT, 768,
        768, 768, 2304, 1, 0, 0, 0, 0, 0, 0, 1.f);
    // fused attention -> ctx [B,S,H] bf16
    fattn<<<dim3(8, 96), 512, 0, stream>>>(qkv, vT, ctx);
    // attn out projection + residual -> res1 fp32
    if (l == 0) {
      gemm_bt<64, 64, true, false, 1, false, false, 6><<<dim3(12, 64, 1), 256, 0, stream>>>(
          ctx, wo_l, res1, bo, x, nullptr, nullptr, nullptr, nullptr, 768,
          768, 768, 768, 1, 0, 0, 0, 0, 0, 0, 1.f);
    } else {
      gemm_bt<64, 64, true, false, 3, false, false, 6><<<dim3(12, 64, 1), 256, 0, stream>>>(
          ctx, wo_l, res1, bo + l * 768, res2, stats2,
          g2 + (l - 1) * 768, be2 + (l - 1) * 768, nullptr, 768,
          768, 768, 768, 1, 0, 0, 0, 0, 0, 0, 1.f);
    }
    layernorm_k<<<dim3(4096), 256, 0, stream>>>(res1, g1 + l * 768, be1 + l * 768,
                                                out1b, stats1, nullptr);
    // FF1: relu(out1 @ W2 + b2) -> h1b bf16
    gemm_bt<64, 64, true, true, 0, true, false, 6><<<dim3(12, 64, 1), 256, 0, stream>>>(
        out1b, w2_l, h1b, b2 + l * 768, nullptr, nullptr, nullptr, nullptr, nullptr, 768,
        768, 768, 768, 1, 0, 0, 0, 0, 0, 0, 1.f);
    // FF2: LN1(res1) + relu(h @ W2 + b2) -> res2 fp32
    gemm_bt<64, 64, true, true, 3, false, false, 6><<<dim3(12, 64, 1), 256, 0, stream>>>(
        h1b, w2_l, res2, b2 + l * 768, res1, stats1,
        g1 + l * 768, be1 + l * 768, nullptr, 768,
        768, 768, 768, 1, 0, 0, 0, 0, 0, 0, 1.f);
    layernorm_k<<<dim3(4096), 256, 0, stream>>>(res2, g2 + l * 768, be2 + l * 768,
                                                xb, stats2, (l == 11) ? (float*)d_out : nullptr);
  }
}